// Round 1
// baseline (594.461 us; speedup 1.0000x reference)
//
#include <hip/hip_runtime.h>

// ---------------------------------------------------------------------------
// FlashMMSequenceMixing (Hyena-style): B=8, L=2048, D=768, ORDER=128, FFT=4096
// Pipeline:
//   1. filter_k:     k[d][l]  (fp32, MLP + sin + decay)            -> ws.kfil
//   2. filter_fft:   K_f[d][0..4095] complex, radix-2 DIF order    -> ws.Kf
//   3. convert_u:    u fp32 -> bf16                                -> ws.ub
//   4. transpose_W:  in_W (768x2304) -> Wt (2304x768) bf16         -> ws.Wt
//      transpose_W:  out_W (768x768) -> W2t (768x768) bf16         -> ws.W2t
//   5. gemm mode0:   X[part][b][d][l] bf16 = (u@in_W+in_b)^T-ish   -> ws.X
//   6. fft_conv:     depthwise conv4 + gate + FFT conv + D_bias + *x2 -> ws.Y
//   7. transpose_Y:  Y (b,d,l) -> Yt ((b,l),d) bf16                -> ws.ub (alias)
//   8. gemm mode1:   out = Yt @ out_W + out_b  (fp32)              -> d_out
// ws total = 162,004,992 bytes
// ---------------------------------------------------------------------------

typedef __bf16 bf16x8 __attribute__((ext_vector_type(8)));
typedef float  f32x4  __attribute__((ext_vector_type(4)));

#define AS1 __attribute__((address_space(1)))
#define AS3 __attribute__((address_space(3)))
#define GLD16(gp, lp) __builtin_amdgcn_global_load_lds((AS1 void*)(void*)(gp), (AS3 void*)(void*)(lp), 16, 0, 0)

__device__ __forceinline__ unsigned short f2b(float f) {
    unsigned u = __builtin_bit_cast(unsigned, f);
    unsigned r = (u + 0x7fffu + ((u >> 16) & 1u)) >> 16;
    return (unsigned short)r;
}
__device__ __forceinline__ float b2f(unsigned short h) {
    unsigned u = ((unsigned)h) << 16;
    return __builtin_bit_cast(float, u);
}

// ------------------------------- filter MLP --------------------------------
__global__ __launch_bounds__(256) void filter_k_kernel(
    const float* __restrict__ z, const float* __restrict__ sf,
    const float* __restrict__ eo, const float* __restrict__ eo_b,
    const float* __restrict__ oo1, const float* __restrict__ oo1_b,
    const float* __restrict__ oo2, const float* __restrict__ oo2_b,
    const float* __restrict__ oh, float* __restrict__ kfil)
{
    __shared__ float h3buf[8][128];
    __shared__ float htmp[2][128];
    const int t = threadIdx.x;
    const int l0 = blockIdx.x * 8;
    const int half = t >> 7;      // 0/1
    const int o = t & 127;
    const float sfo = sf[o];
    for (int p = 0; p < 4; ++p) {
        const int li = p * 2 + half;
        const int l = l0 + li;
        float a = eo_b[o];
        #pragma unroll
        for (int e = 0; e < 5; ++e) a += z[l * 5 + e] * eo[e * 128 + o];
        htmp[half][o] = sinf(sfo * a);
        __syncthreads();
        float a2 = oo1_b[o];
        for (int q = 0; q < 128; ++q) a2 += htmp[half][q] * oo1[q * 128 + o];
        const float h2 = sinf(sfo * a2);
        __syncthreads();
        htmp[half][o] = h2;
        __syncthreads();
        float a3 = oo2_b[o];
        for (int q = 0; q < 128; ++q) a3 += htmp[half][q] * oo2[q * 128 + o];
        h3buf[li][o] = sinf(sfo * a3);
        __syncthreads();
    }
    const float MIND = -3.070113457325394f;   // log(0.01)/1.5
    const float MAXD = -15.350567286626972f;  // log(0.01)/0.3
    for (int c = 0; c < 3; ++c) {
        const int h = t + c * 256;
        float acc[8];
        #pragma unroll
        for (int li = 0; li < 8; ++li) acc[li] = 0.f;
        for (int q = 0; q < 128; ++q) {
            const float w = oh[q * 768 + h];
            #pragma unroll
            for (int li = 0; li < 8; ++li) acc[li] += h3buf[li][q] * w;
        }
        const float delta = fabsf(MIND + (MAXD - MIND) * (float)h * (1.0f / 767.0f));
        #pragma unroll
        for (int li = 0; li < 8; ++li) {
            const int l = l0 + li;
            const float tt = (float)l * (1.0f / 2047.0f);
            kfil[h * 2048 + l] = acc[li] * expf(-tt * delta);
        }
    }
}

// ------------------------------- FFT helpers -------------------------------
// twiddle table holds W_4096^m = exp(-2*pi*i*m/4096) for m in [0,1024);
// W^(m+1024) = W^m * (-i)
__device__ __forceinline__ float2 twget(const float2* tw, int m) {
    float2 w = tw[m & 1023];
    return (m & 1024) ? make_float2(w.y, -w.x) : w;
}

__device__ void fft_fwd(float2* zb, const float2* tw, int t) {
    // radix-2 DIF (Gentleman-Sande), natural in -> bit-reversed out
    for (int hs = 11; hs >= 0; --hs) {
        const int half = 1 << hs;
        for (int it = 0; it < 8; ++it) {
            const int p = it * 256 + t;
            const int j = p & (half - 1);
            const int i0 = ((p >> hs) << (hs + 1)) | j;
            const int i1 = i0 + half;
            const float2 a = zb[i0], b = zb[i1];
            const float2 w = twget(tw, j << (11 - hs));
            zb[i0] = make_float2(a.x + b.x, a.y + b.y);
            const float dx = a.x - b.x, dy = a.y - b.y;
            zb[i1] = make_float2(dx * w.x - dy * w.y, dx * w.y + dy * w.x);
        }
        __syncthreads();
    }
}

__device__ void fft_inv(float2* zb, const float2* tw, int t) {
    // radix-2 DIT (Cooley-Tukey), bit-reversed in -> natural out (unscaled)
    for (int hs = 0; hs <= 11; ++hs) {
        const int half = 1 << hs;
        for (int it = 0; it < 8; ++it) {
            const int p = it * 256 + t;
            const int j = p & (half - 1);
            const int i0 = ((p >> hs) << (hs + 1)) | j;
            const int i1 = i0 + half;
            const float2 a = zb[i0], bb = zb[i1];
            const float2 w = twget(tw, j << (11 - hs)); // conj applied below
            const float bx = bb.x * w.x + bb.y * w.y;
            const float by = bb.y * w.x - bb.x * w.y;
            zb[i0] = make_float2(a.x + bx, a.y + by);
            zb[i1] = make_float2(a.x - bx, a.y - by);
        }
        __syncthreads();
    }
}

__global__ __launch_bounds__(256) void filter_fft_kernel(
    const float* __restrict__ kfil, float2* __restrict__ Kf)
{
    __shared__ float2 zb[4096];
    __shared__ float2 tw[1024];
    const int d = blockIdx.x, t = threadIdx.x;
    for (int m = t; m < 1024; m += 256) {
        float s, c;
        __sincosf((float)m * (-6.283185307179586f / 4096.0f), &s, &c);
        tw[m] = make_float2(c, s);
    }
    for (int it = 0; it < 8; ++it) {
        const int l = it * 256 + t;
        zb[l] = make_float2(kfil[d * 2048 + l], 0.f);
        zb[2048 + l] = make_float2(0.f, 0.f);
    }
    __syncthreads();
    fft_fwd(zb, tw, t);
    for (int it = 0; it < 16; ++it) {
        const int i = it * 256 + t;
        Kf[d * 4096 + i] = zb[i];
    }
}

// --------------------------- conversions/transposes ------------------------
__global__ __launch_bounds__(256) void convert_u_kernel(
    const float* __restrict__ u, unsigned short* __restrict__ ub)
{
    const int g = blockIdx.x * 256 + threadIdx.x;   // < 3145728
    const float4 v = ((const float4*)u)[g];
    uint2 o;
    o.x = (unsigned)f2b(v.x) | ((unsigned)f2b(v.y) << 16);
    o.y = (unsigned)f2b(v.z) | ((unsigned)f2b(v.w) << 16);
    ((uint2*)ub)[g] = o;
}

// W: [K][N] fp32 -> Wt: [N][K] bf16.  grid (N/32, K/32), 256 thr
__global__ __launch_bounds__(256) void transpose_W_kernel(
    const float* __restrict__ W, unsigned short* __restrict__ Wt, int K, int N)
{
    __shared__ float tile[32][33];
    const int n0 = blockIdx.x * 32, k0 = blockIdx.y * 32;
    const int tx = threadIdx.x & 31, ty = threadIdx.x >> 5;
    #pragma unroll
    for (int r = 0; r < 4; ++r) {
        const int kk = ty + r * 8;
        tile[kk][tx] = W[(k0 + kk) * N + n0 + tx];
    }
    __syncthreads();
    #pragma unroll
    for (int r = 0; r < 4; ++r) {
        const int nn = ty + r * 8;
        Wt[(n0 + nn) * K + k0 + tx] = f2b(tile[tx][nn]);
    }
}

// Y: [8][768][2048] bf16 -> Yt: [(b*2048+l)][768] bf16. 12288 blocks
__global__ __launch_bounds__(256) void transpose_Y_kernel(
    const unsigned short* __restrict__ Y, unsigned short* __restrict__ Yt)
{
    __shared__ unsigned short tile[32][34];
    const int bx = blockIdx.x;
    const int l0 = (bx & 63) * 32;
    const int tmp = bx >> 6;
    const int d0 = (tmp % 24) * 32;
    const int b  = tmp / 24;
    const int tx = threadIdx.x & 31, ty = threadIdx.x >> 5;
    #pragma unroll
    for (int r = 0; r < 4; ++r) {
        const int dd = ty + r * 8;
        tile[dd][tx] = Y[(b * 768 + d0 + dd) * 2048 + l0 + tx];
    }
    __syncthreads();
    #pragma unroll
    for (int r = 0; r < 4; ++r) {
        const int ll = ty + r * 8;
        Yt[(b * 2048 + l0 + ll) * 768 + d0 + tx] = tile[tx][ll];
    }
}

// ------------------------------- bf16 GEMM ---------------------------------
// C[row][col] = sum_k A[row][k]*B[col][k], K=768, tiles 128x128, BK=32.
// mode 0: out = X bf16, transposed-channel layout, bias indexed by row (in_b)
// mode 1: out = fp32 row-major [row*768+col], bias indexed by col (out_b)
__global__ __launch_bounds__(256) void gemm_kernel(
    const unsigned short* __restrict__ A,
    const unsigned short* __restrict__ Bm,
    const float* __restrict__ bias,
    unsigned short* __restrict__ outb,
    float* __restrict__ outf,
    int mode)
{
    __shared__ __align__(16) unsigned short As[128 * 32];
    __shared__ __align__(16) unsigned short Bs[128 * 32];
    const int t = threadIdx.x;
    const int wv = t >> 6, lane = t & 63;
    const int row0 = blockIdx.x * 128;
    const int col0 = blockIdx.y * 128;
    const int wr = wv >> 1, wc = wv & 1;

    f32x4 acc[4][4] = {};

    const int g0 = t, g1 = t + 256;
    const unsigned short* gA0 = A + (row0 + (g0 >> 2)) * 768 + (g0 & 3) * 8;
    const unsigned short* gA1 = A + (row0 + (g1 >> 2)) * 768 + (g1 & 3) * 8;
    const unsigned short* gB0 = Bm + (col0 + (g0 >> 2)) * 768 + (g0 & 3) * 8;
    const unsigned short* gB1 = Bm + (col0 + (g1 >> 2)) * 768 + (g1 & 3) * 8;
    char* ldsA0 = (char*)As + wv * 1024;
    char* ldsA1 = (char*)As + 4096 + wv * 1024;
    char* ldsB0 = (char*)Bs + wv * 1024;
    char* ldsB1 = (char*)Bs + 4096 + wv * 1024;

    const int frow = lane & 15;
    const int kq = (lane >> 4) * 8;

    for (int kt = 0; kt < 24; ++kt) {
        GLD16(gA0, ldsA0); GLD16(gA1, ldsA1);
        GLD16(gB0, ldsB0); GLD16(gB1, ldsB1);
        gA0 += 32; gA1 += 32; gB0 += 32; gB1 += 32;
        __syncthreads();
        bf16x8 af[4], bfr[4];
        #pragma unroll
        for (int i = 0; i < 4; ++i) {
            af[i]  = *(const bf16x8*)(As + (wr * 64 + i * 16 + frow) * 32 + kq);
            bfr[i] = *(const bf16x8*)(Bs + (wc * 64 + i * 16 + frow) * 32 + kq);
        }
        #pragma unroll
        for (int i = 0; i < 4; ++i)
            #pragma unroll
            for (int j = 0; j < 4; ++j)
                acc[i][j] = __builtin_amdgcn_mfma_f32_16x16x32_bf16(af[i], bfr[j], acc[i][j], 0, 0, 0);
        __syncthreads();
    }

    if (mode == 0) {
        const int part = row0 / 768;
        const int bb = col0 / 2048;
        unsigned short* Xp = outb + (part * 8 + bb) * 768 * 2048;
        const int dbase = row0 - part * 768 + wr * 64 + (lane >> 4) * 4;
        const int lbase = col0 - bb * 2048 + wc * 64 + frow;
        #pragma unroll
        for (int i = 0; i < 4; ++i) {
            #pragma unroll
            for (int rr = 0; rr < 4; ++rr) {
                const int dd = dbase + i * 16 + rr;
                const float bn = bias[row0 + wr * 64 + (lane >> 4) * 4 + i * 16 + rr];
                #pragma unroll
                for (int j = 0; j < 4; ++j) {
                    const int ll = lbase + j * 16;
                    Xp[dd * 2048 + ll] = f2b(acc[i][j][rr] + bn);
                }
            }
        }
    } else {
        #pragma unroll
        for (int i = 0; i < 4; ++i) {
            #pragma unroll
            for (int rr = 0; rr < 4; ++rr) {
                const int m = row0 + wr * 64 + (lane >> 4) * 4 + i * 16 + rr;
                #pragma unroll
                for (int j = 0; j < 4; ++j) {
                    const int n = col0 + wc * 64 + j * 16 + frow;
                    outf[m * 768 + n] = acc[i][j][rr] + bias[n];
                }
            }
        }
    }
}

// --------------------- fused conv4 + gate + FFT conv -----------------------
// grid (768, 4): d = channel, jp = batch pair. Packs batches (2jp, 2jp+1)
// into one complex FFT; same real filter K_f[d] => W = Z*K, Re/Im = 2 rows.
__global__ __launch_bounds__(256) void fft_conv_kernel(
    const unsigned short* __restrict__ X, const float2* __restrict__ Kf,
    const float* __restrict__ x1_s, const float* __restrict__ x2_s, const float* __restrict__ v_s,
    const float* __restrict__ x1_sb, const float* __restrict__ x2_sb, const float* __restrict__ v_sb,
    const float* __restrict__ D_bias, unsigned short* __restrict__ Y)
{
    __shared__ float2 zb[4096];
    __shared__ float2 tw[1024];
    __shared__ unsigned short vhat[2][2048];
    __shared__ unsigned short cx2s[2][2048];
    const int d = blockIdx.x, jp = blockIdx.y, t = threadIdx.x;

    for (int m = t; m < 1024; m += 256) {
        float s, c;
        __sincosf((float)m * (-6.283185307179586f / 4096.0f), &s, &c);
        tw[m] = make_float2(c, s);
    }
    float w1[4], w2[4], wvv[4];
    #pragma unroll
    for (int j = 0; j < 4; ++j) { w1[j] = x1_s[d * 4 + j]; w2[j] = x2_s[d * 4 + j]; wvv[j] = v_s[d * 4 + j]; }
    const float b1 = x1_sb[d], b2 = x2_sb[d], bv = v_sb[d], Db = D_bias[d];

    #pragma unroll
    for (int r = 0; r < 2; ++r) {
        const int b = jp * 2 + r;
        const unsigned short* px1 = X + ((0 * 8 + b) * 768 + d) * 2048;
        const unsigned short* px2 = X + ((1 * 8 + b) * 768 + d) * 2048;
        const unsigned short* pv  = X + ((2 * 8 + b) * 768 + d) * 2048;
        for (int it = 0; it < 8; ++it) {
            const int l = it * 256 + t;
            float c1 = b1, c2 = b2, cv = bv;
            #pragma unroll
            for (int j = 0; j < 4; ++j) {
                const int s = l - 3 + j;
                if (s >= 0) {
                    c1 += w1[j] * b2f(px1[s]);
                    c2 += w2[j] * b2f(px2[s]);
                    cv += wvv[j] * b2f(pv[s]);
                }
            }
            vhat[r][l] = f2b(cv * c1);
            cx2s[r][l] = f2b(c2);
        }
    }
    __syncthreads();
    for (int it = 0; it < 8; ++it) {
        const int l = it * 256 + t;
        zb[l] = make_float2(b2f(vhat[0][l]), b2f(vhat[1][l]));
        zb[2048 + l] = make_float2(0.f, 0.f);
    }
    __syncthreads();
    fft_fwd(zb, tw, t);
    const float2* kf = Kf + d * 4096;
    for (int it = 0; it < 16; ++it) {
        const int i = it * 256 + t;
        const float2 a = zb[i], k = kf[i];
        zb[i] = make_float2(a.x * k.x - a.y * k.y, a.x * k.y + a.y * k.x);
    }
    __syncthreads();
    fft_inv(zb, tw, t);
    const float invN = 1.0f / 4096.0f;
    for (int it = 0; it < 8; ++it) {
        const int l = it * 256 + t;
        const float2 w = zb[l];
        const float y0 = (w.x * invN + b2f(vhat[0][l]) * Db) * b2f(cx2s[0][l]);
        const float y1 = (w.y * invN + b2f(vhat[1][l]) * Db) * b2f(cx2s[1][l]);
        Y[((jp * 2 + 0) * 768 + d) * 2048 + l] = f2b(y0);
        Y[((jp * 2 + 1) * 768 + d) * 2048 + l] = f2b(y1);
    }
}

// --------------------------------- launch ----------------------------------
extern "C" void kernel_launch(void* const* d_in, const int* in_sizes, int n_in,
                              void* d_out, int out_size, void* d_ws, size_t ws_size,
                              hipStream_t stream)
{
    (void)in_sizes; (void)n_in; (void)out_size; (void)ws_size;
    const float* u      = (const float*)d_in[0];
    const float* in_W   = (const float*)d_in[1];
    const float* in_b   = (const float*)d_in[2];
    const float* out_W  = (const float*)d_in[3];
    const float* out_b  = (const float*)d_in[4];
    const float* x1_s   = (const float*)d_in[5];
    const float* x2_s   = (const float*)d_in[6];
    const float* v_s    = (const float*)d_in[7];
    const float* x1_sb  = (const float*)d_in[8];
    const float* x2_sb  = (const float*)d_in[9];
    const float* v_sb   = (const float*)d_in[10];
    const float* D_bias = (const float*)d_in[11];
    const float* z      = (const float*)d_in[12];
    const float* sf     = (const float*)d_in[13];
    const float* eo     = (const float*)d_in[14];
    const float* eo_b   = (const float*)d_in[15];
    const float* oo1    = (const float*)d_in[16];
    const float* oo1_b  = (const float*)d_in[17];
    const float* oo2    = (const float*)d_in[18];
    const float* oo2_b  = (const float*)d_in[19];
    const float* oh     = (const float*)d_in[20];
    float* out = (float*)d_out;

    char* ws = (char*)d_ws;
    unsigned short* Xbf  = (unsigned short*)(ws + 0);          //  75,497,472 X[3][8][768][2048] bf16
    unsigned short* Ybf  = (unsigned short*)(ws + 75497472);   //  25,165,824 Y[8][768][2048] bf16
    unsigned short* ubYt = (unsigned short*)(ws + 100663296);  //  25,165,824 ub, later aliased as Yt
    unsigned short* Wt   = (unsigned short*)(ws + 125829120);  //   3,538,944 Wt[2304][768] bf16
    unsigned short* W2t  = (unsigned short*)(ws + 129368064);  //   1,179,648 W2t[768][768] bf16
    float*          kfil = (float*)(ws + 130547712);           //   6,291,456 k[768][2048] fp32
    float2*         Kf   = (float2*)(ws + 136839168);          //  25,165,824 K_f[768][4096] cplx
                                                               // total 162,004,992 B

    filter_k_kernel<<<256, 256, 0, stream>>>(z, sf, eo, eo_b, oo1, oo1_b, oo2, oo2_b, oh, kfil);
    filter_fft_kernel<<<768, 256, 0, stream>>>(kfil, Kf);
    convert_u_kernel<<<12288, 256, 0, stream>>>(u, ubYt);
    transpose_W_kernel<<<dim3(72, 24), 256, 0, stream>>>(in_W, Wt, 768, 2304);
    transpose_W_kernel<<<dim3(24, 24), 256, 0, stream>>>(out_W, W2t, 768, 768);
    gemm_kernel<<<dim3(18, 128), 256, 0, stream>>>(Wt, ubYt, in_b, Xbf, nullptr, 0);
    fft_conv_kernel<<<dim3(768, 4), 256, 0, stream>>>(Xbf, Kf, x1_s, x2_s, v_s, x1_sb, x2_sb, v_sb, D_bias, Ybf);
    transpose_Y_kernel<<<12288, 256, 0, stream>>>(Ybf, ubYt);
    gemm_kernel<<<dim3(128, 6), 256, 0, stream>>>(ubYt, W2t, out_b, nullptr, out, 1);
}

// Round 2
// 469.088 us; speedup vs baseline: 1.2673x; 1.2673x over previous
//
#include <hip/hip_runtime.h>

// ---------------------------------------------------------------------------
// FlashMMSequenceMixing (Hyena-style): B=8, L=2048, D=768, ORDER=128, FFT=4096
// R1 -> R2: fft_conv / filter_fft rewritten as 3-round radix-16 REGISTER FFT
// (four-step, 4096 = 16*16*16). Spectrum kept in permuted order in both the
// data and filter paths, so pointwise multiply needs no reordering; inverse
// mirrors forward exactly. 2 LDS transposes per direction instead of 12
// butterfly stages; conv/gate values stay in registers (packed bf16).
// ---------------------------------------------------------------------------

typedef __bf16 bf16x8 __attribute__((ext_vector_type(8)));
typedef float  f32x4  __attribute__((ext_vector_type(4)));

#define AS1 __attribute__((address_space(1)))
#define AS3 __attribute__((address_space(3)))
#define GLD16(gp, lp) __builtin_amdgcn_global_load_lds((AS1 void*)(void*)(gp), (AS3 void*)(void*)(lp), 16, 0, 0)

__device__ __forceinline__ unsigned short f2b(float f) {
    unsigned u = __builtin_bit_cast(unsigned, f);
    unsigned r = (u + 0x7fffu + ((u >> 16) & 1u)) >> 16;
    return (unsigned short)r;
}
__device__ __forceinline__ float b2f(unsigned short h) {
    unsigned u = ((unsigned)h) << 16;
    return __builtin_bit_cast(float, u);
}

__device__ __forceinline__ float2 cmul(float2 a, float2 b) {
    return make_float2(a.x * b.x - a.y * b.y, a.x * b.y + a.y * b.x);
}
__device__ __forceinline__ float2 cadd(float2 a, float2 b) { return make_float2(a.x + b.x, a.y + b.y); }
__device__ __forceinline__ float2 csub(float2 a, float2 b) { return make_float2(a.x - b.x, a.y - b.y); }

// ------------------------- 16-point register DFT ---------------------------
// DIF radix-2, natural in -> natural out (bit-reverse fixed by reg renaming).
// DIR=-1 forward (e^{-i}), DIR=+1 inverse (unscaled). UZ: x[8..15]==0 on входе.
#define BFLY(i,j)   { float2 ta=x[i], tb=x[j]; x[i]=cadd(ta,tb); x[j]=csub(ta,tb); }
#define BFLYW(i,j,w){ float2 ta=x[i], tb=x[j]; x[i]=cadd(ta,tb); x[j]=cmul(csub(ta,tb),(w)); }
#define BFLYI(i,j)  { float2 ta=x[i], tb=x[j]; x[i]=cadd(ta,tb); float2 tt=csub(ta,tb); x[j]=make_float2(-dd*tt.y, dd*tt.x); }
#define CSWAP(i,j)  { float2 tt=x[i]; x[i]=x[j]; x[j]=tt; }

template<int DIR, bool UZ>
__device__ __forceinline__ void dft16(float2* x) {
    const float dd = (float)DIR;
    const float C1 = 0.92387953251128674f, S1 = 0.38268343236508977f, R2 = 0.70710678118654752f;
    const float2 W1 = make_float2( C1, dd*S1);
    const float2 W2 = make_float2( R2, dd*R2);
    const float2 W3 = make_float2( S1, dd*C1);
    const float2 W5 = make_float2(-S1, dd*C1);
    const float2 W6 = make_float2(-R2, dd*R2);
    const float2 W7 = make_float2(-C1, dd*S1);
    if (UZ) {
        x[8]  = x[0];
        x[9]  = cmul(x[1], W1);
        x[10] = cmul(x[2], W2);
        x[11] = cmul(x[3], W3);
        x[12] = make_float2(-dd*x[4].y, dd*x[4].x);
        x[13] = cmul(x[5], W5);
        x[14] = cmul(x[6], W6);
        x[15] = cmul(x[7], W7);
    } else {
        BFLY(0,8); BFLYW(1,9,W1); BFLYW(2,10,W2); BFLYW(3,11,W3);
        BFLYI(4,12); BFLYW(5,13,W5); BFLYW(6,14,W6); BFLYW(7,15,W7);
    }
    BFLY(0,4);  BFLYW(1,5,W2);  BFLYI(2,6);   BFLYW(3,7,W6);
    BFLY(8,12); BFLYW(9,13,W2); BFLYI(10,14); BFLYW(11,15,W6);
    BFLY(0,2);  BFLYI(1,3);  BFLY(4,6);   BFLYI(5,7);
    BFLY(8,10); BFLYI(9,11); BFLY(12,14); BFLYI(13,15);
    BFLY(0,1); BFLY(2,3); BFLY(4,5); BFLY(6,7);
    BFLY(8,9); BFLY(10,11); BFLY(12,13); BFLY(14,15);
    CSWAP(1,8); CSWAP(2,4); CSWAP(3,12); CSWAP(5,10); CSWAP(7,14); CSWAP(11,13);
}

__device__ __forceinline__ void twiddle_mul(float2* x, float ang) {
    float s, c; __sincosf(ang, &s, &c);
    float2 base = make_float2(c, s), w = base;
    #pragma unroll
    for (int k = 1; k < 16; ++k) { x[k] = cmul(x[k], w); w = cmul(w, base); }
}

// ---- 4096-pt forward: thread t holds x[r]=in[r*256+t] (r<8; 8..15 zero) ----
// Output: thread t=(k1*16+k2) holds X[k1+16*k2+256*k3] in x[k3].
// lds must be float2[4352] (16 rows * 272 for T1; 256*17 for T2 — shared).
#define TWO_PI 6.283185307179586f
__device__ __forceinline__ void fft4096_fwd(float2* x, float2* lds, int t) {
    dft16<-1, true>(x);
    twiddle_mul(x, -(float)t * (TWO_PI / 4096.0f));
    #pragma unroll
    for (int k1 = 0; k1 < 16; ++k1) lds[k1 * 272 + t] = x[k1];
    __syncthreads();
    const int hi = t >> 4, lo = t & 15;
    #pragma unroll
    for (int t1 = 0; t1 < 16; ++t1) x[t1] = lds[hi * 272 + t1 * 16 + lo];
    dft16<-1, false>(x);
    twiddle_mul(x, -(float)lo * (TWO_PI / 256.0f));
    __syncthreads();
    #pragma unroll
    for (int k2 = 0; k2 < 16; ++k2) lds[t * 17 + k2] = x[k2];
    __syncthreads();
    #pragma unroll
    for (int t0 = 0; t0 < 16; ++t0) x[t0] = lds[(hi * 16 + t0) * 17 + lo];
    dft16<-1, false>(x);
}

// ---- inverse (unscaled, x16^3): input x[k3] per thread t=(k1*16+k2),
// output x[n1] = 4096 * ifft at n = n1*256 + t.
__device__ __forceinline__ void fft4096_inv(float2* x, float2* lds, int t) {
    const int hi = t >> 4, lo = t & 15;
    dft16<1, false>(x);
    __syncthreads();
    #pragma unroll
    for (int t0 = 0; t0 < 16; ++t0) lds[(hi * 16 + t0) * 17 + lo] = x[t0];
    __syncthreads();
    #pragma unroll
    for (int k2 = 0; k2 < 16; ++k2) x[k2] = lds[t * 17 + k2];
    twiddle_mul(x, (float)lo * (TWO_PI / 256.0f));
    dft16<1, false>(x);
    __syncthreads();
    #pragma unroll
    for (int t1 = 0; t1 < 16; ++t1) lds[hi * 272 + t1 * 16 + lo] = x[t1];
    __syncthreads();
    #pragma unroll
    for (int k1 = 0; k1 < 16; ++k1) x[k1] = lds[k1 * 272 + t];
    twiddle_mul(x, (float)t * (TWO_PI / 4096.0f));
    dft16<1, false>(x);
}

// ------------------------------- filter MLP --------------------------------
__global__ __launch_bounds__(256) void filter_k_kernel(
    const float* __restrict__ z, const float* __restrict__ sf,
    const float* __restrict__ eo, const float* __restrict__ eo_b,
    const float* __restrict__ oo1, const float* __restrict__ oo1_b,
    const float* __restrict__ oo2, const float* __restrict__ oo2_b,
    const float* __restrict__ oh, float* __restrict__ kfil)
{
    __shared__ float h3buf[8][128];
    __shared__ float htmp[2][128];
    const int t = threadIdx.x;
    const int l0 = blockIdx.x * 8;
    const int half = t >> 7;
    const int o = t & 127;
    const float sfo = sf[o];
    for (int p = 0; p < 4; ++p) {
        const int li = p * 2 + half;
        const int l = l0 + li;
        float a = eo_b[o];
        #pragma unroll
        for (int e = 0; e < 5; ++e) a += z[l * 5 + e] * eo[e * 128 + o];
        htmp[half][o] = sinf(sfo * a);
        __syncthreads();
        float a2 = oo1_b[o];
        for (int q = 0; q < 128; ++q) a2 += htmp[half][q] * oo1[q * 128 + o];
        const float h2 = sinf(sfo * a2);
        __syncthreads();
        htmp[half][o] = h2;
        __syncthreads();
        float a3 = oo2_b[o];
        for (int q = 0; q < 128; ++q) a3 += htmp[half][q] * oo2[q * 128 + o];
        h3buf[li][o] = sinf(sfo * a3);
        __syncthreads();
    }
    const float MIND = -3.070113457325394f;
    const float MAXD = -15.350567286626972f;
    for (int c = 0; c < 3; ++c) {
        const int h = t + c * 256;
        float acc[8];
        #pragma unroll
        for (int li = 0; li < 8; ++li) acc[li] = 0.f;
        for (int q = 0; q < 128; ++q) {
            const float w = oh[q * 768 + h];
            #pragma unroll
            for (int li = 0; li < 8; ++li) acc[li] += h3buf[li][q] * w;
        }
        const float delta = fabsf(MIND + (MAXD - MIND) * (float)h * (1.0f / 767.0f));
        #pragma unroll
        for (int li = 0; li < 8; ++li) {
            const int l = l0 + li;
            const float tt = (float)l * (1.0f / 2047.0f);
            kfil[h * 2048 + l] = acc[li] * expf(-tt * delta);
        }
    }
}

// --------------------------- filter FFT ------------------------------------
// Kf layout: [d][k3*256 + v] float2 (permuted spectrum, coalesced both sides)
__global__ __launch_bounds__(256, 4) void filter_fft_kernel(
    const float* __restrict__ kfil, float2* __restrict__ Kf)
{
    __shared__ float2 lds[4352];
    const int d = blockIdx.x, t = threadIdx.x;
    float2 x[16];
    #pragma unroll
    for (int r = 0; r < 8; ++r) x[r] = make_float2(kfil[d * 2048 + r * 256 + t], 0.f);
    fft4096_fwd(x, lds, t);
    #pragma unroll
    for (int k3 = 0; k3 < 16; ++k3) Kf[d * 4096 + k3 * 256 + t] = x[k3];
}

// --------------------------- conversions/transposes ------------------------
__global__ __launch_bounds__(256) void convert_u_kernel(
    const float* __restrict__ u, unsigned short* __restrict__ ub)
{
    const int g = blockIdx.x * 256 + threadIdx.x;
    const float4 v = ((const float4*)u)[g];
    uint2 o;
    o.x = (unsigned)f2b(v.x) | ((unsigned)f2b(v.y) << 16);
    o.y = (unsigned)f2b(v.z) | ((unsigned)f2b(v.w) << 16);
    ((uint2*)ub)[g] = o;
}

__global__ __launch_bounds__(256) void transpose_W_kernel(
    const float* __restrict__ W, unsigned short* __restrict__ Wt, int K, int N)
{
    __shared__ float tile[32][33];
    const int n0 = blockIdx.x * 32, k0 = blockIdx.y * 32;
    const int tx = threadIdx.x & 31, ty = threadIdx.x >> 5;
    #pragma unroll
    for (int r = 0; r < 4; ++r) {
        const int kk = ty + r * 8;
        tile[kk][tx] = W[(k0 + kk) * N + n0 + tx];
    }
    __syncthreads();
    #pragma unroll
    for (int r = 0; r < 4; ++r) {
        const int nn = ty + r * 8;
        Wt[(n0 + nn) * K + k0 + tx] = f2b(tile[tx][nn]);
    }
}

__global__ __launch_bounds__(256) void transpose_Y_kernel(
    const unsigned short* __restrict__ Y, unsigned short* __restrict__ Yt)
{
    __shared__ unsigned short tile[32][34];
    const int bx = blockIdx.x;
    const int l0 = (bx & 63) * 32;
    const int tmp = bx >> 6;
    const int d0 = (tmp % 24) * 32;
    const int b  = tmp / 24;
    const int tx = threadIdx.x & 31, ty = threadIdx.x >> 5;
    #pragma unroll
    for (int r = 0; r < 4; ++r) {
        const int dd = ty + r * 8;
        tile[dd][tx] = Y[(b * 768 + d0 + dd) * 2048 + l0 + tx];
    }
    __syncthreads();
    #pragma unroll
    for (int r = 0; r < 4; ++r) {
        const int ll = ty + r * 8;
        Yt[(b * 2048 + l0 + ll) * 768 + d0 + tx] = tile[tx][ll];
    }
}

// ------------------------------- bf16 GEMM ---------------------------------
__global__ __launch_bounds__(256) void gemm_kernel(
    const unsigned short* __restrict__ A,
    const unsigned short* __restrict__ Bm,
    const float* __restrict__ bias,
    unsigned short* __restrict__ outb,
    float* __restrict__ outf,
    int mode)
{
    __shared__ __align__(16) unsigned short As[128 * 32];
    __shared__ __align__(16) unsigned short Bs[128 * 32];
    const int t = threadIdx.x;
    const int wv = t >> 6, lane = t & 63;
    const int row0 = blockIdx.x * 128;
    const int col0 = blockIdx.y * 128;
    const int wr = wv >> 1, wc = wv & 1;

    f32x4 acc[4][4] = {};

    const int g0 = t, g1 = t + 256;
    const unsigned short* gA0 = A + (row0 + (g0 >> 2)) * 768 + (g0 & 3) * 8;
    const unsigned short* gA1 = A + (row0 + (g1 >> 2)) * 768 + (g1 & 3) * 8;
    const unsigned short* gB0 = Bm + (col0 + (g0 >> 2)) * 768 + (g0 & 3) * 8;
    const unsigned short* gB1 = Bm + (col0 + (g1 >> 2)) * 768 + (g1 & 3) * 8;
    char* ldsA0 = (char*)As + wv * 1024;
    char* ldsA1 = (char*)As + 4096 + wv * 1024;
    char* ldsB0 = (char*)Bs + wv * 1024;
    char* ldsB1 = (char*)Bs + 4096 + wv * 1024;

    const int frow = lane & 15;
    const int kq = (lane >> 4) * 8;

    for (int kt = 0; kt < 24; ++kt) {
        GLD16(gA0, ldsA0); GLD16(gA1, ldsA1);
        GLD16(gB0, ldsB0); GLD16(gB1, ldsB1);
        gA0 += 32; gA1 += 32; gB0 += 32; gB1 += 32;
        __syncthreads();
        bf16x8 af[4], bfr[4];
        #pragma unroll
        for (int i = 0; i < 4; ++i) {
            af[i]  = *(const bf16x8*)(As + (wr * 64 + i * 16 + frow) * 32 + kq);
            bfr[i] = *(const bf16x8*)(Bs + (wc * 64 + i * 16 + frow) * 32 + kq);
        }
        #pragma unroll
        for (int i = 0; i < 4; ++i)
            #pragma unroll
            for (int j = 0; j < 4; ++j)
                acc[i][j] = __builtin_amdgcn_mfma_f32_16x16x32_bf16(af[i], bfr[j], acc[i][j], 0, 0, 0);
        __syncthreads();
    }

    if (mode == 0) {
        const int part = row0 / 768;
        const int bb = col0 / 2048;
        unsigned short* Xp = outb + (part * 8 + bb) * 768 * 2048;
        const int dbase = row0 - part * 768 + wr * 64 + (lane >> 4) * 4;
        const int lbase = col0 - bb * 2048 + wc * 64 + frow;
        #pragma unroll
        for (int i = 0; i < 4; ++i) {
            #pragma unroll
            for (int rr = 0; rr < 4; ++rr) {
                const int dd = dbase + i * 16 + rr;
                const float bn = bias[row0 + wr * 64 + (lane >> 4) * 4 + i * 16 + rr];
                #pragma unroll
                for (int j = 0; j < 4; ++j) {
                    const int ll = lbase + j * 16;
                    Xp[dd * 2048 + ll] = f2b(acc[i][j][rr] + bn);
                }
            }
        }
    } else {
        #pragma unroll
        for (int i = 0; i < 4; ++i) {
            #pragma unroll
            for (int rr = 0; rr < 4; ++rr) {
                const int m = row0 + wr * 64 + (lane >> 4) * 4 + i * 16 + rr;
                #pragma unroll
                for (int j = 0; j < 4; ++j) {
                    const int n = col0 + wc * 64 + j * 16 + frow;
                    outf[m * 768 + n] = acc[i][j][rr] + bias[n];
                }
            }
        }
    }
}

// --------------------- fused conv4 + gate + FFT conv -----------------------
// grid (4, 768): x=jp (batch pair), y=d (channel; adjacent blocks share Kf[d])
__global__ __launch_bounds__(256, 4) void fft_conv_kernel(
    const unsigned short* __restrict__ X, const float2* __restrict__ Kf,
    const float* __restrict__ x1_s, const float* __restrict__ x2_s, const float* __restrict__ v_s,
    const float* __restrict__ x1_sb, const float* __restrict__ x2_sb, const float* __restrict__ v_sb,
    const float* __restrict__ D_bias, unsigned short* __restrict__ Y)
{
    __shared__ float2 lds[4352];
    const int jp = blockIdx.x, d = blockIdx.y, t = threadIdx.x;
    const int b0 = jp * 2, b1 = jp * 2 + 1;

    float w1[4], w2[4], wv[4];
    #pragma unroll
    for (int j = 0; j < 4; ++j) { w1[j] = x1_s[d * 4 + j]; w2[j] = x2_s[d * 4 + j]; wv[j] = v_s[d * 4 + j]; }
    const float bc1 = x1_sb[d], bc2 = x2_sb[d], bcv = v_sb[d], Db = D_bias[d];

    const unsigned short* px1a = X + ((size_t)(0 * 8 + b0) * 768 + d) * 2048;
    const unsigned short* px2a = X + ((size_t)(1 * 8 + b0) * 768 + d) * 2048;
    const unsigned short* pva  = X + ((size_t)(2 * 8 + b0) * 768 + d) * 2048;
    const unsigned short* px1b = X + ((size_t)(0 * 8 + b1) * 768 + d) * 2048;
    const unsigned short* px2b = X + ((size_t)(1 * 8 + b1) * 768 + d) * 2048;
    const unsigned short* pvb  = X + ((size_t)(2 * 8 + b1) * 768 + d) * 2048;

    unsigned vhp[8], c2p[8];
    float2 x[16];
    #pragma unroll
    for (int r = 0; r < 8; ++r) {
        const int l = r * 256 + t;
        float c1a = bc1, c2a = bc2, cva = bcv;
        float c1b = bc1, c2b = bc2, cvb = bcv;
        #pragma unroll
        for (int j = 0; j < 4; ++j) {
            const int s = l - 3 + j;
            if (s >= 0) {
                c1a += w1[j] * b2f(px1a[s]);
                c2a += w2[j] * b2f(px2a[s]);
                cva += wv[j] * b2f(pva[s]);
                c1b += w1[j] * b2f(px1b[s]);
                c2b += w2[j] * b2f(px2b[s]);
                cvb += wv[j] * b2f(pvb[s]);
            }
        }
        const unsigned short va = f2b(cva * c1a), vb = f2b(cvb * c1b);
        vhp[r] = (unsigned)va | ((unsigned)vb << 16);
        c2p[r] = (unsigned)f2b(c2a) | ((unsigned)f2b(c2b) << 16);
        x[r] = make_float2(b2f(va), b2f(vb));
    }

    fft4096_fwd(x, lds, t);

    const float2* kf = Kf + (size_t)d * 4096;
    #pragma unroll
    for (int k3 = 0; k3 < 16; ++k3) x[k3] = cmul(x[k3], kf[k3 * 256 + t]);

    fft4096_inv(x, lds, t);

    const float invN = 1.0f / 4096.0f;
    unsigned short* ya = Y + ((size_t)b0 * 768 + d) * 2048;
    unsigned short* yb = Y + ((size_t)b1 * 768 + d) * 2048;
    #pragma unroll
    for (int n1 = 0; n1 < 8; ++n1) {
        const int l = n1 * 256 + t;
        const float va = b2f((unsigned short)(vhp[n1] & 0xffff));
        const float vb = b2f((unsigned short)(vhp[n1] >> 16));
        const float ca = b2f((unsigned short)(c2p[n1] & 0xffff));
        const float cb = b2f((unsigned short)(c2p[n1] >> 16));
        ya[l] = f2b((x[n1].x * invN + va * Db) * ca);
        yb[l] = f2b((x[n1].y * invN + vb * Db) * cb);
    }
}

// --------------------------------- launch ----------------------------------
extern "C" void kernel_launch(void* const* d_in, const int* in_sizes, int n_in,
                              void* d_out, int out_size, void* d_ws, size_t ws_size,
                              hipStream_t stream)
{
    (void)in_sizes; (void)n_in; (void)out_size; (void)ws_size;
    const float* u      = (const float*)d_in[0];
    const float* in_W   = (const float*)d_in[1];
    const float* in_b   = (const float*)d_in[2];
    const float* out_W  = (const float*)d_in[3];
    const float* out_b  = (const float*)d_in[4];
    const float* x1_s   = (const float*)d_in[5];
    const float* x2_s   = (const float*)d_in[6];
    const float* v_s    = (const float*)d_in[7];
    const float* x1_sb  = (const float*)d_in[8];
    const float* x2_sb  = (const float*)d_in[9];
    const float* v_sb   = (const float*)d_in[10];
    const float* D_bias = (const float*)d_in[11];
    const float* z      = (const float*)d_in[12];
    const float* sf     = (const float*)d_in[13];
    const float* eo     = (const float*)d_in[14];
    const float* eo_b   = (const float*)d_in[15];
    const float* oo1    = (const float*)d_in[16];
    const float* oo1_b  = (const float*)d_in[17];
    const float* oo2    = (const float*)d_in[18];
    const float* oo2_b  = (const float*)d_in[19];
    const float* oh     = (const float*)d_in[20];
    float* out = (float*)d_out;

    char* ws = (char*)d_ws;
    unsigned short* Xbf  = (unsigned short*)(ws + 0);          //  75,497,472 X[3][8][768][2048] bf16
    unsigned short* Ybf  = (unsigned short*)(ws + 75497472);   //  25,165,824 Y[8][768][2048] bf16
    unsigned short* ubYt = (unsigned short*)(ws + 100663296);  //  25,165,824 ub, later aliased as Yt
    unsigned short* Wt   = (unsigned short*)(ws + 125829120);  //   3,538,944 Wt[2304][768] bf16
    unsigned short* W2t  = (unsigned short*)(ws + 129368064);  //   1,179,648 W2t[768][768] bf16
    float*          kfil = (float*)(ws + 130547712);           //   6,291,456 k[768][2048] fp32
    float2*         Kf   = (float2*)(ws + 136839168);          //  25,165,824 K_f[768][16][256] cplx (permuted)

    filter_k_kernel<<<256, 256, 0, stream>>>(z, sf, eo, eo_b, oo1, oo1_b, oo2, oo2_b, oh, kfil);
    filter_fft_kernel<<<768, 256, 0, stream>>>(kfil, Kf);
    convert_u_kernel<<<12288, 256, 0, stream>>>(u, ubYt);
    transpose_W_kernel<<<dim3(72, 24), 256, 0, stream>>>(in_W, Wt, 768, 2304);
    transpose_W_kernel<<<dim3(24, 24), 256, 0, stream>>>(out_W, W2t, 768, 768);
    gemm_kernel<<<dim3(18, 128), 256, 0, stream>>>(Wt, ubYt, in_b, Xbf, nullptr, 0);
    fft_conv_kernel<<<dim3(4, 768), 256, 0, stream>>>(Xbf, Kf, x1_s, x2_s, v_s, x1_sb, x2_sb, v_sb, D_bias, Ybf);
    transpose_Y_kernel<<<12288, 256, 0, stream>>>(Ybf, ubYt);
    gemm_kernel<<<dim3(128, 6), 256, 0, stream>>>(ubYt, W2t, out_b, nullptr, out, 1);
}

// Round 4
// 428.497 us; speedup vs baseline: 1.3873x; 1.0947x over previous
//
#include <hip/hip_runtime.h>

// ---------------------------------------------------------------------------
// FlashMMSequenceMixing (Hyena-style): B=8, L=2048, D=768, ORDER=128, FFT=4096
// R3 resubmit (R3 bench was an infra failure — container died, no signal):
//  * fft_conv grid (4,768)->(768,4): blocks sharing Kf[d] are 768 apart
//    (768%8==0 -> same XCD) => Kf L2 reuse instead of ~2.8x HBM over-fetch.
//  * fft_conv conv phase: contiguous mapping (thread t owns l=8t..8t+7),
//    12 vector loads instead of 192 scalar; staged via LDS to the strided
//    FFT mapping. Kf prefetched to regs (overlaps fwd FFT). Tree twiddles.
//  * gemm mode0 grid (18,128)->(128,18) with col-fast indexing: blocks
//    sharing a B col-tile map to one XCD => B fetched ~once.
// ---------------------------------------------------------------------------

typedef __bf16 bf16x8 __attribute__((ext_vector_type(8)));
typedef float  f32x4  __attribute__((ext_vector_type(4)));

#define AS1 __attribute__((address_space(1)))
#define AS3 __attribute__((address_space(3)))
#define GLD16(gp, lp) __builtin_amdgcn_global_load_lds((AS1 void*)(void*)(gp), (AS3 void*)(void*)(lp), 16, 0, 0)

__device__ __forceinline__ unsigned short f2b(float f) {
    unsigned u = __builtin_bit_cast(unsigned, f);
    unsigned r = (u + 0x7fffu + ((u >> 16) & 1u)) >> 16;
    return (unsigned short)r;
}
__device__ __forceinline__ float b2f(unsigned short h) {
    unsigned u = ((unsigned)h) << 16;
    return __builtin_bit_cast(float, u);
}
__device__ __forceinline__ float b2f_lo(unsigned u) {
    return __builtin_bit_cast(float, u << 16);
}
__device__ __forceinline__ float b2f_hi(unsigned u) {
    return __builtin_bit_cast(float, u & 0xffff0000u);
}

__device__ __forceinline__ float2 cmul(float2 a, float2 b) {
    return make_float2(a.x * b.x - a.y * b.y, a.x * b.y + a.y * b.x);
}
__device__ __forceinline__ float2 cadd(float2 a, float2 b) { return make_float2(a.x + b.x, a.y + b.y); }
__device__ __forceinline__ float2 csub(float2 a, float2 b) { return make_float2(a.x - b.x, a.y - b.y); }

// ------------------------- 16-point register DFT ---------------------------
#define BFLY(i,j)   { float2 ta=x[i], tb=x[j]; x[i]=cadd(ta,tb); x[j]=csub(ta,tb); }
#define BFLYW(i,j,w){ float2 ta=x[i], tb=x[j]; x[i]=cadd(ta,tb); x[j]=cmul(csub(ta,tb),(w)); }
#define BFLYI(i,j)  { float2 ta=x[i], tb=x[j]; x[i]=cadd(ta,tb); float2 tt=csub(ta,tb); x[j]=make_float2(-dd*tt.y, dd*tt.x); }
#define CSWAP(i,j)  { float2 tt=x[i]; x[i]=x[j]; x[j]=tt; }

template<int DIR, bool UZ>
__device__ __forceinline__ void dft16(float2* x) {
    const float dd = (float)DIR;
    const float C1 = 0.92387953251128674f, S1 = 0.38268343236508977f, R2 = 0.70710678118654752f;
    const float2 W1 = make_float2( C1, dd*S1);
    const float2 W2 = make_float2( R2, dd*R2);
    const float2 W3 = make_float2( S1, dd*C1);
    const float2 W5 = make_float2(-S1, dd*C1);
    const float2 W6 = make_float2(-R2, dd*R2);
    const float2 W7 = make_float2(-C1, dd*S1);
    if (UZ) {
        x[8]  = x[0];
        x[9]  = cmul(x[1], W1);
        x[10] = cmul(x[2], W2);
        x[11] = cmul(x[3], W3);
        x[12] = make_float2(-dd*x[4].y, dd*x[4].x);
        x[13] = cmul(x[5], W5);
        x[14] = cmul(x[6], W6);
        x[15] = cmul(x[7], W7);
    } else {
        BFLY(0,8); BFLYW(1,9,W1); BFLYW(2,10,W2); BFLYW(3,11,W3);
        BFLYI(4,12); BFLYW(5,13,W5); BFLYW(6,14,W6); BFLYW(7,15,W7);
    }
    BFLY(0,4);  BFLYW(1,5,W2);  BFLYI(2,6);   BFLYW(3,7,W6);
    BFLY(8,12); BFLYW(9,13,W2); BFLYI(10,14); BFLYW(11,15,W6);
    BFLY(0,2);  BFLYI(1,3);  BFLY(4,6);   BFLYI(5,7);
    BFLY(8,10); BFLYI(9,11); BFLY(12,14); BFLYI(13,15);
    BFLY(0,1); BFLY(2,3); BFLY(4,5); BFLY(6,7);
    BFLY(8,9); BFLY(10,11); BFLY(12,13); BFLY(14,15);
    CSWAP(1,8); CSWAP(2,4); CSWAP(3,12); CSWAP(5,10); CSWAP(7,14); CSWAP(11,13);
}

// log-depth twiddle powers (serial chain 15 -> depth 4)
__device__ __forceinline__ void twiddle_mul(float2* x, float ang) {
    float s, c; __sincosf(ang, &s, &c);
    float2 w[16];
    w[1] = make_float2(c, s);
    w[2] = cmul(w[1], w[1]);
    w[3] = cmul(w[2], w[1]);  w[4] = cmul(w[2], w[2]);
    w[5] = cmul(w[4], w[1]);  w[6] = cmul(w[4], w[2]);
    w[7] = cmul(w[4], w[3]);  w[8] = cmul(w[4], w[4]);
    w[9]  = cmul(w[8], w[1]); w[10] = cmul(w[8], w[2]);
    w[11] = cmul(w[8], w[3]); w[12] = cmul(w[8], w[4]);
    w[13] = cmul(w[8], w[5]); w[14] = cmul(w[8], w[6]);
    w[15] = cmul(w[8], w[7]);
    #pragma unroll
    for (int k = 1; k < 16; ++k) x[k] = cmul(x[k], w[k]);
}

#define TWO_PI 6.283185307179586f
__device__ __forceinline__ void fft4096_fwd(float2* x, float2* lds, int t) {
    dft16<-1, true>(x);
    twiddle_mul(x, -(float)t * (TWO_PI / 4096.0f));
    #pragma unroll
    for (int k1 = 0; k1 < 16; ++k1) lds[k1 * 272 + t] = x[k1];
    __syncthreads();
    const int hi = t >> 4, lo = t & 15;
    #pragma unroll
    for (int t1 = 0; t1 < 16; ++t1) x[t1] = lds[hi * 272 + t1 * 16 + lo];
    dft16<-1, false>(x);
    twiddle_mul(x, -(float)lo * (TWO_PI / 256.0f));
    __syncthreads();
    #pragma unroll
    for (int k2 = 0; k2 < 16; ++k2) lds[t * 17 + k2] = x[k2];
    __syncthreads();
    #pragma unroll
    for (int t0 = 0; t0 < 16; ++t0) x[t0] = lds[(hi * 16 + t0) * 17 + lo];
    dft16<-1, false>(x);
}

__device__ __forceinline__ void fft4096_inv(float2* x, float2* lds, int t) {
    const int hi = t >> 4, lo = t & 15;
    dft16<1, false>(x);
    __syncthreads();
    #pragma unroll
    for (int t0 = 0; t0 < 16; ++t0) lds[(hi * 16 + t0) * 17 + lo] = x[t0];
    __syncthreads();
    #pragma unroll
    for (int k2 = 0; k2 < 16; ++k2) x[k2] = lds[t * 17 + k2];
    twiddle_mul(x, (float)lo * (TWO_PI / 256.0f));
    dft16<1, false>(x);
    __syncthreads();
    #pragma unroll
    for (int t1 = 0; t1 < 16; ++t1) lds[hi * 272 + t1 * 16 + lo] = x[t1];
    __syncthreads();
    #pragma unroll
    for (int k1 = 0; k1 < 16; ++k1) x[k1] = lds[k1 * 272 + t];
    twiddle_mul(x, (float)t * (TWO_PI / 4096.0f));
    dft16<1, false>(x);
}

// ------------------------------- filter MLP --------------------------------
__global__ __launch_bounds__(256) void filter_k_kernel(
    const float* __restrict__ z, const float* __restrict__ sf,
    const float* __restrict__ eo, const float* __restrict__ eo_b,
    const float* __restrict__ oo1, const float* __restrict__ oo1_b,
    const float* __restrict__ oo2, const float* __restrict__ oo2_b,
    const float* __restrict__ oh, float* __restrict__ kfil)
{
    __shared__ float h3buf[8][128];
    __shared__ float htmp[2][128];
    const int t = threadIdx.x;
    const int l0 = blockIdx.x * 8;
    const int half = t >> 7;
    const int o = t & 127;
    const float sfo = sf[o];
    for (int p = 0; p < 4; ++p) {
        const int li = p * 2 + half;
        const int l = l0 + li;
        float a = eo_b[o];
        #pragma unroll
        for (int e = 0; e < 5; ++e) a += z[l * 5 + e] * eo[e * 128 + o];
        htmp[half][o] = sinf(sfo * a);
        __syncthreads();
        float a2 = oo1_b[o];
        for (int q = 0; q < 128; ++q) a2 += htmp[half][q] * oo1[q * 128 + o];
        const float h2 = sinf(sfo * a2);
        __syncthreads();
        htmp[half][o] = h2;
        __syncthreads();
        float a3 = oo2_b[o];
        for (int q = 0; q < 128; ++q) a3 += htmp[half][q] * oo2[q * 128 + o];
        h3buf[li][o] = sinf(sfo * a3);
        __syncthreads();
    }
    const float MIND = -3.070113457325394f;
    const float MAXD = -15.350567286626972f;
    for (int c = 0; c < 3; ++c) {
        const int h = t + c * 256;
        float acc[8];
        #pragma unroll
        for (int li = 0; li < 8; ++li) acc[li] = 0.f;
        for (int q = 0; q < 128; ++q) {
            const float w = oh[q * 768 + h];
            #pragma unroll
            for (int li = 0; li < 8; ++li) acc[li] += h3buf[li][q] * w;
        }
        const float delta = fabsf(MIND + (MAXD - MIND) * (float)h * (1.0f / 767.0f));
        #pragma unroll
        for (int li = 0; li < 8; ++li) {
            const int l = l0 + li;
            const float tt = (float)l * (1.0f / 2047.0f);
            kfil[h * 2048 + l] = acc[li] * expf(-tt * delta);
        }
    }
}

// --------------------------- filter FFT ------------------------------------
__global__ __launch_bounds__(256, 4) void filter_fft_kernel(
    const float* __restrict__ kfil, float2* __restrict__ Kf)
{
    __shared__ float2 lds[4352];
    const int d = blockIdx.x, t = threadIdx.x;
    float2 x[16];
    #pragma unroll
    for (int r = 0; r < 8; ++r) x[r] = make_float2(kfil[d * 2048 + r * 256 + t], 0.f);
    fft4096_fwd(x, lds, t);
    #pragma unroll
    for (int k3 = 0; k3 < 16; ++k3) Kf[d * 4096 + k3 * 256 + t] = x[k3];
}

// --------------------------- conversions/transposes ------------------------
__global__ __launch_bounds__(256) void convert_u_kernel(
    const float* __restrict__ u, unsigned short* __restrict__ ub)
{
    const int g = blockIdx.x * 256 + threadIdx.x;
    const float4 v = ((const float4*)u)[g];
    uint2 o;
    o.x = (unsigned)f2b(v.x) | ((unsigned)f2b(v.y) << 16);
    o.y = (unsigned)f2b(v.z) | ((unsigned)f2b(v.w) << 16);
    ((uint2*)ub)[g] = o;
}

__global__ __launch_bounds__(256) void transpose_W_kernel(
    const float* __restrict__ W, unsigned short* __restrict__ Wt, int K, int N)
{
    __shared__ float tile[32][33];
    const int n0 = blockIdx.x * 32, k0 = blockIdx.y * 32;
    const int tx = threadIdx.x & 31, ty = threadIdx.x >> 5;
    #pragma unroll
    for (int r = 0; r < 4; ++r) {
        const int kk = ty + r * 8;
        tile[kk][tx] = W[(k0 + kk) * N + n0 + tx];
    }
    __syncthreads();
    #pragma unroll
    for (int r = 0; r < 4; ++r) {
        const int nn = ty + r * 8;
        Wt[(n0 + nn) * K + k0 + tx] = f2b(tile[tx][nn]);
    }
}

__global__ __launch_bounds__(256) void transpose_Y_kernel(
    const unsigned short* __restrict__ Y, unsigned short* __restrict__ Yt)
{
    __shared__ unsigned short tile[32][34];
    const int bx = blockIdx.x;
    const int l0 = (bx & 63) * 32;
    const int tmp = bx >> 6;
    const int d0 = (tmp % 24) * 32;
    const int b  = tmp / 24;
    const int tx = threadIdx.x & 31, ty = threadIdx.x >> 5;
    #pragma unroll
    for (int r = 0; r < 4; ++r) {
        const int dd = ty + r * 8;
        tile[dd][tx] = Y[(b * 768 + d0 + dd) * 2048 + l0 + tx];
    }
    __syncthreads();
    #pragma unroll
    for (int r = 0; r < 4; ++r) {
        const int ll = ty + r * 8;
        Yt[(b * 2048 + l0 + ll) * 768 + d0 + tx] = tile[tx][ll];
    }
}

// ------------------------------- bf16 GEMM ---------------------------------
// mode 0: launched dim3(nCol, nRow) (col-fast => same-B blocks on same XCD)
// mode 1: launched dim3(nRow, nCol) (row-fast => same-A blocks on same XCD)
__global__ __launch_bounds__(256) void gemm_kernel(
    const unsigned short* __restrict__ A,
    const unsigned short* __restrict__ Bm,
    const float* __restrict__ bias,
    unsigned short* __restrict__ outb,
    float* __restrict__ outf,
    int mode)
{
    __shared__ __align__(16) unsigned short As[128 * 32];
    __shared__ __align__(16) unsigned short Bs[128 * 32];
    const int t = threadIdx.x;
    const int wv = t >> 6, lane = t & 63;
    const int row0 = (mode == 0 ? blockIdx.y : blockIdx.x) * 128;
    const int col0 = (mode == 0 ? blockIdx.x : blockIdx.y) * 128;
    const int wr = wv >> 1, wc = wv & 1;

    f32x4 acc[4][4] = {};

    const int g0 = t, g1 = t + 256;
    const unsigned short* gA0 = A + (row0 + (g0 >> 2)) * 768 + (g0 & 3) * 8;
    const unsigned short* gA1 = A + (row0 + (g1 >> 2)) * 768 + (g1 & 3) * 8;
    const unsigned short* gB0 = Bm + (col0 + (g0 >> 2)) * 768 + (g0 & 3) * 8;
    const unsigned short* gB1 = Bm + (col0 + (g1 >> 2)) * 768 + (g1 & 3) * 8;
    char* ldsA0 = (char*)As + wv * 1024;
    char* ldsA1 = (char*)As + 4096 + wv * 1024;
    char* ldsB0 = (char*)Bs + wv * 1024;
    char* ldsB1 = (char*)Bs + 4096 + wv * 1024;

    const int frow = lane & 15;
    const int kq = (lane >> 4) * 8;

    for (int kt = 0; kt < 24; ++kt) {
        GLD16(gA0, ldsA0); GLD16(gA1, ldsA1);
        GLD16(gB0, ldsB0); GLD16(gB1, ldsB1);
        gA0 += 32; gA1 += 32; gB0 += 32; gB1 += 32;
        __syncthreads();
        bf16x8 af[4], bfr[4];
        #pragma unroll
        for (int i = 0; i < 4; ++i) {
            af[i]  = *(const bf16x8*)(As + (wr * 64 + i * 16 + frow) * 32 + kq);
            bfr[i] = *(const bf16x8*)(Bs + (wc * 64 + i * 16 + frow) * 32 + kq);
        }
        #pragma unroll
        for (int i = 0; i < 4; ++i)
            #pragma unroll
            for (int j = 0; j < 4; ++j)
                acc[i][j] = __builtin_amdgcn_mfma_f32_16x16x32_bf16(af[i], bfr[j], acc[i][j], 0, 0, 0);
        __syncthreads();
    }

    if (mode == 0) {
        const int part = row0 / 768;
        const int bb = col0 / 2048;
        unsigned short* Xp = outb + (part * 8 + bb) * 768 * 2048;
        const int dbase = row0 - part * 768 + wr * 64 + (lane >> 4) * 4;
        const int lbase = col0 - bb * 2048 + wc * 64 + frow;
        #pragma unroll
        for (int i = 0; i < 4; ++i) {
            #pragma unroll
            for (int rr = 0; rr < 4; ++rr) {
                const int dd = dbase + i * 16 + rr;
                const float bn = bias[row0 + wr * 64 + (lane >> 4) * 4 + i * 16 + rr];
                #pragma unroll
                for (int j = 0; j < 4; ++j) {
                    const int ll = lbase + j * 16;
                    Xp[dd * 2048 + ll] = f2b(acc[i][j][rr] + bn);
                }
            }
        }
    } else {
        #pragma unroll
        for (int i = 0; i < 4; ++i) {
            #pragma unroll
            for (int rr = 0; rr < 4; ++rr) {
                const int m = row0 + wr * 64 + (lane >> 4) * 4 + i * 16 + rr;
                #pragma unroll
                for (int j = 0; j < 4; ++j) {
                    const int n = col0 + wc * 64 + j * 16 + frow;
                    outf[m * 768 + n] = acc[i][j][rr] + bias[n];
                }
            }
        }
    }
}

// --------------------- fused conv4 + gate + FFT conv -----------------------
// conv over l=8t..8t+7 with vectorized loads; out8[i] = bias + sum_j w[j]*X[l-3+j]
__device__ __forceinline__ void conv6(const unsigned short* __restrict__ p,
                                      const float* w, float bias, int t, float* out8)
{
    const uint4 m = *(const uint4*)(p + 8 * t);
    uint2 q = make_uint2(0u, 0u);
    if (t) q = *(const uint2*)(p + 8 * t - 4);
    float s[12];
    s[0] = b2f_lo(q.x); s[1] = b2f_hi(q.x); s[2] = b2f_lo(q.y); s[3] = b2f_hi(q.y);
    s[4] = b2f_lo(m.x); s[5] = b2f_hi(m.x); s[6] = b2f_lo(m.y); s[7] = b2f_hi(m.y);
    s[8] = b2f_lo(m.z); s[9] = b2f_hi(m.z); s[10] = b2f_lo(m.w); s[11] = b2f_hi(m.w);
    #pragma unroll
    for (int i = 0; i < 8; ++i)
        out8[i] = bias + w[0] * s[i + 1] + w[1] * s[i + 2] + w[2] * s[i + 3] + w[3] * s[i + 4];
}

// grid (768, 4): x=d (same-d blocks 768 apart -> same XCD -> Kf L2 reuse)
__global__ __launch_bounds__(256, 4) void fft_conv_kernel(
    const unsigned short* __restrict__ X, const float2* __restrict__ Kf,
    const float* __restrict__ x1_s, const float* __restrict__ x2_s, const float* __restrict__ v_s,
    const float* __restrict__ x1_sb, const float* __restrict__ x2_sb, const float* __restrict__ v_sb,
    const float* __restrict__ D_bias, unsigned short* __restrict__ Y)
{
    __shared__ __align__(16) float2 lds[4352];
    unsigned* ldsu = (unsigned*)lds;   // staging: [0..2047]=vhat pairs, [2048..4095]=x2 pairs
    const int d = blockIdx.x, jp = blockIdx.y, t = threadIdx.x;
    const int b0 = jp * 2, b1 = b0 + 1;

    float w1[4], w2[4], wv[4];
    #pragma unroll
    for (int j = 0; j < 4; ++j) { w1[j] = x1_s[d * 4 + j]; w2[j] = x2_s[d * 4 + j]; wv[j] = v_s[d * 4 + j]; }
    const float bc1 = x1_sb[d], bc2 = x2_sb[d], bcv = v_sb[d], Db = D_bias[d];

    const unsigned short* px1a = X + ((size_t)(0 * 8 + b0) * 768 + d) * 2048;
    const unsigned short* px2a = X + ((size_t)(1 * 8 + b0) * 768 + d) * 2048;
    const unsigned short* pva  = X + ((size_t)(2 * 8 + b0) * 768 + d) * 2048;
    const unsigned short* px1b = X + ((size_t)(0 * 8 + b1) * 768 + d) * 2048;
    const unsigned short* px2b = X + ((size_t)(1 * 8 + b1) * 768 + d) * 2048;
    const unsigned short* pvb  = X + ((size_t)(2 * 8 + b1) * 768 + d) * 2048;

    // ---- conv phase (contiguous mapping) ----
    {
        float x1a[8], x2a[8], vva[8];
        conv6(px1a, w1, bc1, t, x1a);
        conv6(px2a, w2, bc2, t, x2a);
        conv6(pva,  wv, bcv, t, vva);
        float x1b[8], x2b[8], vvb[8];
        conv6(px1b, w1, bc1, t, x1b);
        conv6(px2b, w2, bc2, t, x2b);
        conv6(pvb,  wv, bcv, t, vvb);
        unsigned vh_pk[8], c2_pk[8];
        #pragma unroll
        for (int i = 0; i < 8; ++i) {
            vh_pk[i] = (unsigned)f2b(vva[i] * x1a[i]) | ((unsigned)f2b(vvb[i] * x1b[i]) << 16);
            c2_pk[i] = (unsigned)f2b(x2a[i]) | ((unsigned)f2b(x2b[i]) << 16);
        }
        *(uint4*)(ldsu + 8 * t)        = make_uint4(vh_pk[0], vh_pk[1], vh_pk[2], vh_pk[3]);
        *(uint4*)(ldsu + 8 * t + 4)    = make_uint4(vh_pk[4], vh_pk[5], vh_pk[6], vh_pk[7]);
        *(uint4*)(ldsu + 2048 + 8 * t)     = make_uint4(c2_pk[0], c2_pk[1], c2_pk[2], c2_pk[3]);
        *(uint4*)(ldsu + 2048 + 8 * t + 4) = make_uint4(c2_pk[4], c2_pk[5], c2_pk[6], c2_pk[7]);
    }
    __syncthreads();

    // ---- read back in strided FFT mapping ----
    unsigned vhp[8], c2p[8];
    float2 x[16];
    #pragma unroll
    for (int r = 0; r < 8; ++r) {
        const unsigned u = ldsu[r * 256 + t];
        vhp[r] = u;
        x[r] = make_float2(b2f_lo(u), b2f_hi(u));
    }
    #pragma unroll
    for (int r = 0; r < 8; ++r) c2p[r] = ldsu[2048 + r * 256 + t];

    // prefetch filter spectrum (overlaps forward FFT)
    const float2* kf = Kf + (size_t)d * 4096;
    float2 kfr[16];
    #pragma unroll
    for (int k3 = 0; k3 < 16; ++k3) kfr[k3] = kf[k3 * 256 + t];

    __syncthreads();   // staging reads done before T1 overwrites buffer

    fft4096_fwd(x, lds, t);
    #pragma unroll
    for (int k3 = 0; k3 < 16; ++k3) x[k3] = cmul(x[k3], kfr[k3]);
    fft4096_inv(x, lds, t);

    const float invN = 1.0f / 4096.0f;
    unsigned short* ya = Y + ((size_t)b0 * 768 + d) * 2048;
    unsigned short* yb = Y + ((size_t)b1 * 768 + d) * 2048;
    #pragma unroll
    for (int n1 = 0; n1 < 8; ++n1) {
        const int l = n1 * 256 + t;
        const float va = b2f_lo(vhp[n1]);
        const float vb = b2f_hi(vhp[n1]);
        const float ca = b2f_lo(c2p[n1]);
        const float cb = b2f_hi(c2p[n1]);
        ya[l] = f2b((x[n1].x * invN + va * Db) * ca);
        yb[l] = f2b((x[n1].y * invN + vb * Db) * cb);
    }
}

// --------------------------------- launch ----------------------------------
extern "C" void kernel_launch(void* const* d_in, const int* in_sizes, int n_in,
                              void* d_out, int out_size, void* d_ws, size_t ws_size,
                              hipStream_t stream)
{
    (void)in_sizes; (void)n_in; (void)out_size; (void)ws_size;
    const float* u      = (const float*)d_in[0];
    const float* in_W   = (const float*)d_in[1];
    const float* in_b   = (const float*)d_in[2];
    const float* out_W  = (const float*)d_in[3];
    const float* out_b  = (const float*)d_in[4];
    const float* x1_s   = (const float*)d_in[5];
    const float* x2_s   = (const float*)d_in[6];
    const float* v_s    = (const float*)d_in[7];
    const float* x1_sb  = (const float*)d_in[8];
    const float* x2_sb  = (const float*)d_in[9];
    const float* v_sb   = (const float*)d_in[10];
    const float* D_bias = (const float*)d_in[11];
    const float* z      = (const float*)d_in[12];
    const float* sf     = (const float*)d_in[13];
    const float* eo     = (const float*)d_in[14];
    const float* eo_b   = (const float*)d_in[15];
    const float* oo1    = (const float*)d_in[16];
    const float* oo1_b  = (const float*)d_in[17];
    const float* oo2    = (const float*)d_in[18];
    const float* oo2_b  = (const float*)d_in[19];
    const float* oh     = (const float*)d_in[20];
    float* out = (float*)d_out;

    char* ws = (char*)d_ws;
    unsigned short* Xbf  = (unsigned short*)(ws + 0);          //  75,497,472 X[3][8][768][2048] bf16
    unsigned short* Ybf  = (unsigned short*)(ws + 75497472);   //  25,165,824 Y[8][768][2048] bf16
    unsigned short* ubYt = (unsigned short*)(ws + 100663296);  //  25,165,824 ub, later aliased as Yt
    unsigned short* Wt   = (unsigned short*)(ws + 125829120);  //   3,538,944 Wt[2304][768] bf16
    unsigned short* W2t  = (unsigned short*)(ws + 129368064);  //   1,179,648 W2t[768][768] bf16
    float*          kfil = (float*)(ws + 130547712);           //   6,291,456 k[768][2048] fp32
    float2*         Kf   = (float2*)(ws + 136839168);          //  25,165,824 K_f[768][16][256] cplx (permuted)

    filter_k_kernel<<<256, 256, 0, stream>>>(z, sf, eo, eo_b, oo1, oo1_b, oo2, oo2_b, oh, kfil);
    filter_fft_kernel<<<768, 256, 0, stream>>>(kfil, Kf);
    convert_u_kernel<<<12288, 256, 0, stream>>>(u, ubYt);
    transpose_W_kernel<<<dim3(72, 24), 256, 0, stream>>>(in_W, Wt, 768, 2304);
    transpose_W_kernel<<<dim3(24, 24), 256, 0, stream>>>(out_W, W2t, 768, 768);
    gemm_kernel<<<dim3(128, 18), 256, 0, stream>>>(Wt, ubYt, in_b, Xbf, nullptr, 0);
    fft_conv_kernel<<<dim3(768, 4), 256, 0, stream>>>(Xbf, Kf, x1_s, x2_s, v_s, x1_sb, x2_sb, v_sb, D_bias, Ybf);
    transpose_Y_kernel<<<12288, 256, 0, stream>>>(Ybf, ubYt);
    gemm_kernel<<<dim3(128, 6), 256, 0, stream>>>(ubYt, W2t, out_b, nullptr, out, 1);
}

// Round 7
// 402.404 us; speedup vs baseline: 1.4773x; 1.0648x over previous
//
#include <hip/hip_runtime.h>

// ---------------------------------------------------------------------------
// FlashMMSequenceMixing (Hyena-style): B=8, L=2048, D=768, ORDER=128, FFT=4096
// R6 -> R7: two HW-race fixes in the pipelined GEMM (R5/R6 replay failures):
//  1) end-of-body barrier now drains lgkmcnt(0) first: without it a wave can
//     cross the barrier with stage-CUR ds_reads in flight (MFMAs are register
//     ops, not fenced by asm memory clobbers, so their lgkm waits can sink
//     below the barrier) while another wave's DMA overwrites the stage.
//  2) no dummy tail prefetches: 22 prefetching bodies + 2 drain tails
//     (vmcnt(4)/vmcnt(0)), so vmcnt==0 at loop exit — no in-flight LDS DMА
//     at s_endpgm corrupting a reallocated workgroup's LDS.
// Pipeline kept: 3-stage LDS, s_waitcnt vmcnt(8)+s_barrier entry sync,
// XOR chunk swizzle (conflict-free fragment reads).
// ---------------------------------------------------------------------------

typedef __bf16 bf16x8 __attribute__((ext_vector_type(8)));
typedef float  f32x4  __attribute__((ext_vector_type(4)));

#define AS1 __attribute__((address_space(1)))
#define AS3 __attribute__((address_space(3)))
#define GLD16(gp, lp) __builtin_amdgcn_global_load_lds((AS1 void*)(void*)(gp), (AS3 void*)(void*)(lp), 16, 0, 0)

// compiler-visible fences (memory clobber pins LDS/global ops to program order)
#define PIPE_VM_BARRIER(N)  __asm__ __volatile__("s_waitcnt vmcnt(" #N ")\n\ts_barrier" ::: "memory")
#define PIPE_LGKM_BARRIER   __asm__ __volatile__("s_waitcnt lgkmcnt(0)\n\ts_barrier" ::: "memory")

__device__ __forceinline__ unsigned short f2b(float f) {
    unsigned u = __builtin_bit_cast(unsigned, f);
    unsigned r = (u + 0x7fffu + ((u >> 16) & 1u)) >> 16;
    return (unsigned short)r;
}
__device__ __forceinline__ float b2f(unsigned short h) {
    unsigned u = ((unsigned)h) << 16;
    return __builtin_bit_cast(float, u);
}
__device__ __forceinline__ float b2f_lo(unsigned u) {
    return __builtin_bit_cast(float, u << 16);
}
__device__ __forceinline__ float b2f_hi(unsigned u) {
    return __builtin_bit_cast(float, u & 0xffff0000u);
}

__device__ __forceinline__ float2 cmul(float2 a, float2 b) {
    return make_float2(a.x * b.x - a.y * b.y, a.x * b.y + a.y * b.x);
}
__device__ __forceinline__ float2 cadd(float2 a, float2 b) { return make_float2(a.x + b.x, a.y + b.y); }
__device__ __forceinline__ float2 csub(float2 a, float2 b) { return make_float2(a.x - b.x, a.y - b.y); }

// ------------------------- 16-point register DFT ---------------------------
#define BFLY(i,j)   { float2 ta=x[i], tb=x[j]; x[i]=cadd(ta,tb); x[j]=csub(ta,tb); }
#define BFLYW(i,j,w){ float2 ta=x[i], tb=x[j]; x[i]=cadd(ta,tb); x[j]=cmul(csub(ta,tb),(w)); }
#define BFLYI(i,j)  { float2 ta=x[i], tb=x[j]; x[i]=cadd(ta,tb); float2 tt=csub(ta,tb); x[j]=make_float2(-dd*tt.y, dd*tt.x); }
#define CSWAP(i,j)  { float2 tt=x[i]; x[i]=x[j]; x[j]=tt; }

template<int DIR, bool UZ>
__device__ __forceinline__ void dft16(float2* x) {
    const float dd = (float)DIR;
    const float C1 = 0.92387953251128674f, S1 = 0.38268343236508977f, R2 = 0.70710678118654752f;
    const float2 W1 = make_float2( C1, dd*S1);
    const float2 W2 = make_float2( R2, dd*R2);
    const float2 W3 = make_float2( S1, dd*C1);
    const float2 W5 = make_float2(-S1, dd*C1);
    const float2 W6 = make_float2(-R2, dd*R2);
    const float2 W7 = make_float2(-C1, dd*S1);
    if (UZ) {
        x[8]  = x[0];
        x[9]  = cmul(x[1], W1);
        x[10] = cmul(x[2], W2);
        x[11] = cmul(x[3], W3);
        x[12] = make_float2(-dd*x[4].y, dd*x[4].x);
        x[13] = cmul(x[5], W5);
        x[14] = cmul(x[6], W6);
        x[15] = cmul(x[7], W7);
    } else {
        BFLY(0,8); BFLYW(1,9,W1); BFLYW(2,10,W2); BFLYW(3,11,W3);
        BFLYI(4,12); BFLYW(5,13,W5); BFLYW(6,14,W6); BFLYW(7,15,W7);
    }
    BFLY(0,4);  BFLYW(1,5,W2);  BFLYI(2,6);   BFLYW(3,7,W6);
    BFLY(8,12); BFLYW(9,13,W2); BFLYI(10,14); BFLYW(11,15,W6);
    BFLY(0,2);  BFLYI(1,3);  BFLY(4,6);   BFLYI(5,7);
    BFLY(8,10); BFLYI(9,11); BFLY(12,14); BFLYI(13,15);
    BFLY(0,1); BFLY(2,3); BFLY(4,5); BFLY(6,7);
    BFLY(8,9); BFLY(10,11); BFLY(12,13); BFLY(14,15);
    CSWAP(1,8); CSWAP(2,4); CSWAP(3,12); CSWAP(5,10); CSWAP(7,14); CSWAP(11,13);
}

// log-depth twiddle powers (serial chain 15 -> depth 4)
__device__ __forceinline__ void twiddle_mul(float2* x, float ang) {
    float s, c; __sincosf(ang, &s, &c);
    float2 w[16];
    w[1] = make_float2(c, s);
    w[2] = cmul(w[1], w[1]);
    w[3] = cmul(w[2], w[1]);  w[4] = cmul(w[2], w[2]);
    w[5] = cmul(w[4], w[1]);  w[6] = cmul(w[4], w[2]);
    w[7] = cmul(w[4], w[3]);  w[8] = cmul(w[4], w[4]);
    w[9]  = cmul(w[8], w[1]); w[10] = cmul(w[8], w[2]);
    w[11] = cmul(w[8], w[3]); w[12] = cmul(w[8], w[4]);
    w[13] = cmul(w[8], w[5]); w[14] = cmul(w[8], w[6]);
    w[15] = cmul(w[8], w[7]);
    #pragma unroll
    for (int k = 1; k < 16; ++k) x[k] = cmul(x[k], w[k]);
}

#define TWO_PI 6.283185307179586f
__device__ __forceinline__ void fft4096_fwd(float2* x, float2* lds, int t) {
    dft16<-1, true>(x);
    twiddle_mul(x, -(float)t * (TWO_PI / 4096.0f));
    #pragma unroll
    for (int k1 = 0; k1 < 16; ++k1) lds[k1 * 272 + t] = x[k1];
    __syncthreads();
    const int hi = t >> 4, lo = t & 15;
    #pragma unroll
    for (int t1 = 0; t1 < 16; ++t1) x[t1] = lds[hi * 272 + t1 * 16 + lo];
    dft16<-1, false>(x);
    twiddle_mul(x, -(float)lo * (TWO_PI / 256.0f));
    __syncthreads();
    #pragma unroll
    for (int k2 = 0; k2 < 16; ++k2) lds[t * 17 + k2] = x[k2];
    __syncthreads();
    #pragma unroll
    for (int t0 = 0; t0 < 16; ++t0) x[t0] = lds[(hi * 16 + t0) * 17 + lo];
    dft16<-1, false>(x);
}

__device__ __forceinline__ void fft4096_inv(float2* x, float2* lds, int t) {
    const int hi = t >> 4, lo = t & 15;
    dft16<1, false>(x);
    __syncthreads();
    #pragma unroll
    for (int t0 = 0; t0 < 16; ++t0) lds[(hi * 16 + t0) * 17 + lo] = x[t0];
    __syncthreads();
    #pragma unroll
    for (int k2 = 0; k2 < 16; ++k2) x[k2] = lds[t * 17 + k2];
    twiddle_mul(x, (float)lo * (TWO_PI / 256.0f));
    dft16<1, false>(x);
    __syncthreads();
    #pragma unroll
    for (int t1 = 0; t1 < 16; ++t1) lds[hi * 272 + t1 * 16 + lo] = x[t1];
    __syncthreads();
    #pragma unroll
    for (int k1 = 0; k1 < 16; ++k1) x[k1] = lds[k1 * 272 + t];
    twiddle_mul(x, (float)t * (TWO_PI / 4096.0f));
    dft16<1, false>(x);
}

// ------------------------------- filter MLP --------------------------------
__global__ __launch_bounds__(256) void filter_k_kernel(
    const float* __restrict__ z, const float* __restrict__ sf,
    const float* __restrict__ eo, const float* __restrict__ eo_b,
    const float* __restrict__ oo1, const float* __restrict__ oo1_b,
    const float* __restrict__ oo2, const float* __restrict__ oo2_b,
    const float* __restrict__ oh, float* __restrict__ kfil)
{
    __shared__ float h3buf[8][128];
    __shared__ float htmp[2][128];
    const int t = threadIdx.x;
    const int l0 = blockIdx.x * 8;
    const int half = t >> 7;
    const int o = t & 127;
    const float sfo = sf[o];
    for (int p = 0; p < 4; ++p) {
        const int li = p * 2 + half;
        const int l = l0 + li;
        float a = eo_b[o];
        #pragma unroll
        for (int e = 0; e < 5; ++e) a += z[l * 5 + e] * eo[e * 128 + o];
        htmp[half][o] = sinf(sfo * a);
        __syncthreads();
        float a2 = oo1_b[o];
        for (int q = 0; q < 128; ++q) a2 += htmp[half][q] * oo1[q * 128 + o];
        const float h2 = sinf(sfo * a2);
        __syncthreads();
        htmp[half][o] = h2;
        __syncthreads();
        float a3 = oo2_b[o];
        for (int q = 0; q < 128; ++q) a3 += htmp[half][q] * oo2[q * 128 + o];
        h3buf[li][o] = sinf(sfo * a3);
        __syncthreads();
    }
    const float MIND = -3.070113457325394f;
    const float MAXD = -15.350567286626972f;
    for (int c = 0; c < 3; ++c) {
        const int h = t + c * 256;
        float acc[8];
        #pragma unroll
        for (int li = 0; li < 8; ++li) acc[li] = 0.f;
        for (int q = 0; q < 128; ++q) {
            const float w = oh[q * 768 + h];
            #pragma unroll
            for (int li = 0; li < 8; ++li) acc[li] += h3buf[li][q] * w;
        }
        const float delta = fabsf(MIND + (MAXD - MIND) * (float)h * (1.0f / 767.0f));
        #pragma unroll
        for (int li = 0; li < 8; ++li) {
            const int l = l0 + li;
            const float tt = (float)l * (1.0f / 2047.0f);
            kfil[h * 2048 + l] = acc[li] * expf(-tt * delta);
        }
    }
}

// --------------------------- filter FFT ------------------------------------
__global__ __launch_bounds__(256, 4) void filter_fft_kernel(
    const float* __restrict__ kfil, float2* __restrict__ Kf)
{
    __shared__ float2 lds[4352];
    const int d = blockIdx.x, t = threadIdx.x;
    float2 x[16];
    #pragma unroll
    for (int r = 0; r < 8; ++r) x[r] = make_float2(kfil[d * 2048 + r * 256 + t], 0.f);
    fft4096_fwd(x, lds, t);
    #pragma unroll
    for (int k3 = 0; k3 < 16; ++k3) Kf[d * 4096 + k3 * 256 + t] = x[k3];
}

// --------------------------- conversions/transposes ------------------------
__global__ __launch_bounds__(256) void convert_u_kernel(
    const float* __restrict__ u, unsigned short* __restrict__ ub)
{
    const int g = blockIdx.x * 256 + threadIdx.x;
    const float4 v = ((const float4*)u)[g];
    uint2 o;
    o.x = (unsigned)f2b(v.x) | ((unsigned)f2b(v.y) << 16);
    o.y = (unsigned)f2b(v.z) | ((unsigned)f2b(v.w) << 16);
    ((uint2*)ub)[g] = o;
}

__global__ __launch_bounds__(256) void transpose_W_kernel(
    const float* __restrict__ W, unsigned short* __restrict__ Wt, int K, int N)
{
    __shared__ float tile[32][33];
    const int n0 = blockIdx.x * 32, k0 = blockIdx.y * 32;
    const int tx = threadIdx.x & 31, ty = threadIdx.x >> 5;
    #pragma unroll
    for (int r = 0; r < 4; ++r) {
        const int kk = ty + r * 8;
        tile[kk][tx] = W[(k0 + kk) * N + n0 + tx];
    }
    __syncthreads();
    #pragma unroll
    for (int r = 0; r < 4; ++r) {
        const int nn = ty + r * 8;
        Wt[(n0 + nn) * K + k0 + tx] = f2b(tile[tx][nn]);
    }
}

__global__ __launch_bounds__(256) void transpose_Y_kernel(
    const unsigned short* __restrict__ Y, unsigned short* __restrict__ Yt)
{
    __shared__ unsigned short tile[32][34];
    const int bx = blockIdx.x;
    const int l0 = (bx & 63) * 32;
    const int tmp = bx >> 6;
    const int d0 = (tmp % 24) * 32;
    const int b  = tmp / 24;
    const int tx = threadIdx.x & 31, ty = threadIdx.x >> 5;
    #pragma unroll
    for (int r = 0; r < 4; ++r) {
        const int dd = ty + r * 8;
        tile[dd][tx] = Y[(b * 768 + d0 + dd) * 2048 + l0 + tx];
    }
    __syncthreads();
    #pragma unroll
    for (int r = 0; r < 4; ++r) {
        const int ll = ty + r * 8;
        Yt[(b * 2048 + l0 + ll) * 768 + d0 + tx] = tile[tx][ll];
    }
}

// ------------------------------- bf16 GEMM ---------------------------------
// 3-stage pipelined K-loop: 22 prefetching bodies + 2 drain tails.
// Entry sync: s_waitcnt vmcnt(N)+s_barrier (oldest stage drained, all waves).
// Exit sync: s_waitcnt lgkmcnt(0)+s_barrier (this wave's ds_reads landed in
// VGPRs before any wave may overwrite the stage).
// mode 0: launched dim3(nCol, nRow) (col-fast => same-B blocks on same XCD)
// mode 1: launched dim3(nRow, nCol)
__global__ __launch_bounds__(256, 3) void gemm_kernel(
    const unsigned short* __restrict__ A,
    const unsigned short* __restrict__ Bm,
    const float* __restrict__ bias,
    unsigned short* __restrict__ outb,
    float* __restrict__ outf,
    int mode)
{
    __shared__ __align__(16) unsigned short As[3 * 4096];   // 3 stages x 8 KB
    __shared__ __align__(16) unsigned short Bs[3 * 4096];
    const int t = threadIdx.x;
    const int wv = t >> 6, lane = t & 63;
    const int row0 = (mode == 0 ? blockIdx.y : blockIdx.x) * 128;
    const int col0 = (mode == 0 ? blockIdx.x : blockIdx.y) * 128;
    const int wr = wv >> 1, wc = wv & 1;

    f32x4 acc[4][4] = {};

    // staging: thread t loads slot t (rows 0..63) and slot t+256 (rows 64..127);
    // within a row's 64B the chunk is XOR-swizzled so LDS slot (row, c) holds
    // data chunk c ^ swz(row), swz(r) = ((r>>1)^(r>>3))&3.
    const int r0 = t >> 2;
    const int r1 = r0 + 64;
    const int c0 = (t & 3) ^ (((r0 >> 1) ^ (r0 >> 3)) & 3);
    const int c1 = (t & 3) ^ (((r1 >> 1) ^ (r1 >> 3)) & 3);
    const unsigned short* gA0 = A + (row0 + r0) * 768 + c0 * 8;
    const unsigned short* gA1 = A + (row0 + r1) * 768 + c1 * 8;
    const unsigned short* gB0 = Bm + (col0 + r0) * 768 + c0 * 8;
    const unsigned short* gB1 = Bm + (col0 + r1) * 768 + c1 * 8;

    // fragment read offsets (ushort units), swizzle-matched
    const int frow = lane & 15, kc = lane >> 4;
    int offA[4], offB[4];
    #pragma unroll
    for (int i = 0; i < 4; ++i) {
        const int ra = wr * 64 + i * 16 + frow;
        const int rb = wc * 64 + i * 16 + frow;
        offA[i] = ra * 32 + ((kc ^ (((ra >> 1) ^ (ra >> 3)) & 3)) << 3);
        offB[i] = rb * 32 + ((kc ^ (((rb >> 1) ^ (rb >> 3)) & 3)) << 3);
    }

    // prologue: fill stage 0 (tile 0) and stage 1 (tile 1)
    GLD16(gA0, (char*)As + wv * 1024);
    GLD16(gA1, (char*)As + 4096 + wv * 1024);
    GLD16(gB0, (char*)Bs + wv * 1024);
    GLD16(gB1, (char*)Bs + 4096 + wv * 1024);
    gA0 += 32; gA1 += 32; gB0 += 32; gB1 += 32;
    GLD16(gA0, (char*)As + 8192 + wv * 1024);
    GLD16(gA1, (char*)As + 8192 + 4096 + wv * 1024);
    GLD16(gB0, (char*)Bs + 8192 + wv * 1024);
    GLD16(gB1, (char*)Bs + 8192 + 4096 + wv * 1024);
    gA0 += 32; gA1 += 32; gB0 += 32; gB1 += 32;

#define GEMM_FRAG_MFMA(CUR)                                                   \
        const unsigned short* Ast = As + (CUR) * 4096;                        \
        const unsigned short* Bst = Bs + (CUR) * 4096;                        \
        bf16x8 af[4], bfr[4];                                                 \
        _Pragma("unroll") for (int i = 0; i < 4; ++i) {                       \
            af[i]  = *(const bf16x8*)(Ast + offA[i]);                         \
            bfr[i] = *(const bf16x8*)(Bst + offB[i]);                         \
        }                                                                     \
        _Pragma("unroll") for (int i = 0; i < 4; ++i)                         \
            _Pragma("unroll") for (int j = 0; j < 4; ++j)                     \
                acc[i][j] = __builtin_amdgcn_mfma_f32_16x16x32_bf16(          \
                    af[i], bfr[j], acc[i][j], 0, 0, 0);

#define GEMM_BODY(CUR, PF)                                                    \
    {                                                                         \
        GLD16(gA0, (char*)As + (PF) * 8192 + wv * 1024);                      \
        GLD16(gA1, (char*)As + (PF) * 8192 + 4096 + wv * 1024);               \
        GLD16(gB0, (char*)Bs + (PF) * 8192 + wv * 1024);                      \
        GLD16(gB1, (char*)Bs + (PF) * 8192 + 4096 + wv * 1024);               \
        gA0 += 32; gA1 += 32; gB0 += 32; gB1 += 32;                           \
        PIPE_VM_BARRIER(8);  /* oldest stage's 4 DMAs drained, all waves */   \
        GEMM_FRAG_MFMA(CUR)                                                   \
        PIPE_LGKM_BARRIER;   /* my ds_reads landed; safe to overwrite CUR */  \
    }

#define GEMM_TAIL(CUR, N)                                                     \
    {                                                                         \
        PIPE_VM_BARRIER(N);                                                   \
        GEMM_FRAG_MFMA(CUR)                                                   \
    }

    // bodies 0..21 consume tiles 0..21, prefetch tiles 2..23
    for (int kq = 0; kq < 7; ++kq) {
        GEMM_BODY(0, 2)
        GEMM_BODY(1, 0)
        GEMM_BODY(2, 1)
    }
    GEMM_BODY(0, 2)      // body 21: consume tile 21, prefetch tile 23
    GEMM_TAIL(1, 4)      // tile 22
    GEMM_TAIL(2, 0)      // tile 23; vmcnt==0 at exit
#undef GEMM_BODY
#undef GEMM_TAIL
#undef GEMM_FRAG_MFMA

    if (mode == 0) {
        const int part = row0 / 768;
        const int bb = col0 / 2048;
        unsigned short* Xp = outb + (part * 8 + bb) * 768 * 2048;
        const int dbase = row0 - part * 768 + wr * 64 + (lane >> 4) * 4;
        const int lbase = col0 - bb * 2048 + wc * 64 + frow;
        #pragma unroll
        for (int i = 0; i < 4; ++i) {
            #pragma unroll
            for (int rr = 0; rr < 4; ++rr) {
                const int dd = dbase + i * 16 + rr;
                const float bn = bias[row0 + wr * 64 + (lane >> 4) * 4 + i * 16 + rr];
                #pragma unroll
                for (int j = 0; j < 4; ++j) {
                    const int ll = lbase + j * 16;
                    Xp[dd * 2048 + ll] = f2b(acc[i][j][rr] + bn);
                }
            }
        }
    } else {
        #pragma unroll
        for (int i = 0; i < 4; ++i) {
            #pragma unroll
            for (int rr = 0; rr < 4; ++rr) {
                const int m = row0 + wr * 64 + (lane >> 4) * 4 + i * 16 + rr;
                #pragma unroll
                for (int j = 0; j < 4; ++j) {
                    const int n = col0 + wc * 64 + j * 16 + frow;
                    outf[m * 768 + n] = acc[i][j][rr] + bias[n];
                }
            }
        }
    }
}

// --------------------- fused conv4 + gate + FFT conv -----------------------
__device__ __forceinline__ void conv6(const unsigned short* __restrict__ p,
                                      const float* w, float bias, int t, float* out8)
{
    const uint4 m = *(const uint4*)(p + 8 * t);
    uint2 q = make_uint2(0u, 0u);
    if (t) q = *(const uint2*)(p + 8 * t - 4);
    float s[12];
    s[0] = b2f_lo(q.x); s[1] = b2f_hi(q.x); s[2] = b2f_lo(q.y); s[3] = b2f_hi(q.y);
    s[4] = b2f_lo(m.x); s[5] = b2f_hi(m.x); s[6] = b2f_lo(m.y); s[7] = b2f_hi(m.y);
    s[8] = b2f_lo(m.z); s[9] = b2f_hi(m.z); s[10] = b2f_lo(m.w); s[11] = b2f_hi(m.w);
    #pragma unroll
    for (int i = 0; i < 8; ++i)
        out8[i] = bias + w[0] * s[i + 1] + w[1] * s[i + 2] + w[2] * s[i + 3] + w[3] * s[i + 4];
}

// grid (768, 4): x=d (same-d blocks 768 apart -> same XCD -> Kf L2 reuse)
__global__ __launch_bounds__(256, 4) void fft_conv_kernel(
    const unsigned short* __restrict__ X, const float2* __restrict__ Kf,
    const float* __restrict__ x1_s, const float* __restrict__ x2_s, const float* __restrict__ v_s,
    const float* __restrict__ x1_sb, const float* __restrict__ x2_sb, const float* __restrict__ v_sb,
    const float* __restrict__ D_bias, unsigned short* __restrict__ Y)
{
    __shared__ __align__(16) float2 lds[4352];
    unsigned* ldsu = (unsigned*)lds;
    const int d = blockIdx.x, jp = blockIdx.y, t = threadIdx.x;
    const int b0 = jp * 2, b1 = b0 + 1;

    float w1[4], w2[4], wv[4];
    #pragma unroll
    for (int j = 0; j < 4; ++j) { w1[j] = x1_s[d * 4 + j]; w2[j] = x2_s[d * 4 + j]; wv[j] = v_s[d * 4 + j]; }
    const float bc1 = x1_sb[d], bc2 = x2_sb[d], bcv = v_sb[d], Db = D_bias[d];

    const unsigned short* px1a = X + ((size_t)(0 * 8 + b0) * 768 + d) * 2048;
    const unsigned short* px2a = X + ((size_t)(1 * 8 + b0) * 768 + d) * 2048;
    const unsigned short* pva  = X + ((size_t)(2 * 8 + b0) * 768 + d) * 2048;
    const unsigned short* px1b = X + ((size_t)(0 * 8 + b1) * 768 + d) * 2048;
    const unsigned short* px2b = X + ((size_t)(1 * 8 + b1) * 768 + d) * 2048;
    const unsigned short* pvb  = X + ((size_t)(2 * 8 + b1) * 768 + d) * 2048;

    {
        float x1a[8], x2a[8], vva[8];
        conv6(px1a, w1, bc1, t, x1a);
        conv6(px2a, w2, bc2, t, x2a);
        conv6(pva,  wv, bcv, t, vva);
        float x1b[8], x2b[8], vvb[8];
        conv6(px1b, w1, bc1, t, x1b);
        conv6(px2b, w2, bc2, t, x2b);
        conv6(pvb,  wv, bcv, t, vvb);
        unsigned vh_pk[8], c2_pk[8];
        #pragma unroll
        for (int i = 0; i < 8; ++i) {
            vh_pk[i] = (unsigned)f2b(vva[i] * x1a[i]) | ((unsigned)f2b(vvb[i] * x1b[i]) << 16);
            c2_pk[i] = (unsigned)f2b(x2a[i]) | ((unsigned)f2b(x2b[i]) << 16);
        }
        *(uint4*)(ldsu + 8 * t)        = make_uint4(vh_pk[0], vh_pk[1], vh_pk[2], vh_pk[3]);
        *(uint4*)(ldsu + 8 * t + 4)    = make_uint4(vh_pk[4], vh_pk[5], vh_pk[6], vh_pk[7]);
        *(uint4*)(ldsu + 2048 + 8 * t)     = make_uint4(c2_pk[0], c2_pk[1], c2_pk[2], c2_pk[3]);
        *(uint4*)(ldsu + 2048 + 8 * t + 4) = make_uint4(c2_pk[4], c2_pk[5], c2_pk[6], c2_pk[7]);
    }
    __syncthreads();

    unsigned vhp[8], c2p[8];
    float2 x[16];
    #pragma unroll
    for (int r = 0; r < 8; ++r) {
        const unsigned u = ldsu[r * 256 + t];
        vhp[r] = u;
        x[r] = make_float2(b2f_lo(u), b2f_hi(u));
    }
    #pragma unroll
    for (int r = 0; r < 8; ++r) c2p[r] = ldsu[2048 + r * 256 + t];

    const float2* kf = Kf + (size_t)d * 4096;
    float2 kfr[16];
    #pragma unroll
    for (int k3 = 0; k3 < 16; ++k3) kfr[k3] = kf[k3 * 256 + t];

    __syncthreads();

    fft4096_fwd(x, lds, t);
    #pragma unroll
    for (int k3 = 0; k3 < 16; ++k3) x[k3] = cmul(x[k3], kfr[k3]);
    fft4096_inv(x, lds, t);

    const float invN = 1.0f / 4096.0f;
    unsigned short* ya = Y + ((size_t)b0 * 768 + d) * 2048;
    unsigned short* yb = Y + ((size_t)b1 * 768 + d) * 2048;
    #pragma unroll
    for (int n1 = 0; n1 < 8; ++n1) {
        const int l = n1 * 256 + t;
        const float va = b2f_lo(vhp[n1]);
        const float vb = b2f_hi(vhp[n1]);
        const float ca = b2f_lo(c2p[n1]);
        const float cb = b2f_hi(c2p[n1]);
        ya[l] = f2b((x[n1].x * invN + va * Db) * ca);
        yb[l] = f2b((x[n1].y * invN + vb * Db) * cb);
    }
}

// --------------------------------- launch ----------------------------------
extern "C" void kernel_launch(void* const* d_in, const int* in_sizes, int n_in,
                              void* d_out, int out_size, void* d_ws, size_t ws_size,
                              hipStream_t stream)
{
    (void)in_sizes; (void)n_in; (void)out_size; (void)ws_size;
    const float* u      = (const float*)d_in[0];
    const float* in_W   = (const float*)d_in[1];
    const float* in_b   = (const float*)d_in[2];
    const float* out_W  = (const float*)d_in[3];
    const float* out_b  = (const float*)d_in[4];
    const float* x1_s   = (const float*)d_in[5];
    const float* x2_s   = (const float*)d_in[6];
    const float* v_s    = (const float*)d_in[7];
    const float* x1_sb  = (const float*)d_in[8];
    const float* x2_sb  = (const float*)d_in[9];
    const float* v_sb   = (const float*)d_in[10];
    const float* D_bias = (const float*)d_in[11];
    const float* z      = (const float*)d_in[12];
    const float* sf     = (const float*)d_in[13];
    const float* eo     = (const float*)d_in[14];
    const float* eo_b   = (const float*)d_in[15];
    const float* oo1    = (const float*)d_in[16];
    const float* oo1_b  = (const float*)d_in[17];
    const float* oo2    = (const float*)d_in[18];
    const float* oo2_b  = (const float*)d_in[19];
    const float* oh     = (const float*)d_in[20];
    float* out = (float*)d_out;

    char* ws = (char*)d_ws;
    unsigned short* Xbf  = (unsigned short*)(ws + 0);          //  75,497,472 X[3][8][768][2048] bf16
    unsigned short* Ybf  = (unsigned short*)(ws + 75497472);   //  25,165,824 Y[8][768][2048] bf16
    unsigned short* ubYt = (unsigned short*)(ws + 100663296);  //  25,165,824 ub, later aliased as Yt
    unsigned short* Wt   = (unsigned short*)(ws + 125829120);  //   3,538,944 Wt[2304][768] bf16
    unsigned short* W2t  = (unsigned short*)(ws + 129368064);  //   1,179,648 W2t[768][768] bf16
    float*          kfil = (float*)(ws + 130547712);           //   6,291,456 k[768][2048] fp32
    float2*         Kf   = (float2*)(ws + 136839168);          //  25,165,824 K_f[768][16][256] cplx (permuted)

    filter_k_kernel<<<256, 256, 0, stream>>>(z, sf, eo, eo_b, oo1, oo1_b, oo2, oo2_b, oh, kfil);
    filter_fft_kernel<<<768, 256, 0, stream>>>(kfil, Kf);
    convert_u_kernel<<<12288, 256, 0, stream>>>(u, ubYt);
    transpose_W_kernel<<<dim3(72, 24), 256, 0, stream>>>(in_W, Wt, 768, 2304);
    transpose_W_kernel<<<dim3(24, 24), 256, 0, stream>>>(out_W, W2t, 768, 768);
    gemm_kernel<<<dim3(128, 18), 256, 0, stream>>>(Wt, ubYt, in_b, Xbf, nullptr, 0);
    fft_conv_kernel<<<dim3(768, 4), 256, 0, stream>>>(Xbf, Kf, x1_s, x2_s, v_s, x1_sb, x2_sb, v_sb, D_bias, Ybf);
    transpose_Y_kernel<<<12288, 256, 0, stream>>>(Ybf, ubYt);
    gemm_kernel<<<dim3(128, 6), 256, 0, stream>>>(ubYt, W2t, out_b, nullptr, out, 1);
}